// Round 1
// baseline (614.623 us; speedup 1.0000x reference)
//
#include <hip/hip_runtime.h>
#include <hip/hip_bf16.h>

#define N_NODES 50000
#define HID 128
#define CLS 64

// ---------------- degree count ----------------
__global__ void count_kernel(const int* __restrict__ col, int* __restrict__ cnt, int E) {
    int e = blockIdx.x * blockDim.x + threadIdx.x;
    if (e < E) atomicAdd(&cnt[col[e]], 1);
}

// ---------------- dinv = rsqrt(deg+1) ----------------
__global__ void dinv_kernel(const int* __restrict__ cnt, float* __restrict__ dinv, int n) {
    int i = blockIdx.x * blockDim.x + threadIdx.x;
    if (i < n) dinv[i] = rsqrtf((float)cnt[i] + 1.0f);
}

// ---------------- single-block exclusive scan over N counts ----------------
// 1024 threads, each handles a contiguous chunk; one block-level Hillis-Steele.
__global__ void scan_kernel(const int* __restrict__ cnt, int* __restrict__ row_ptr,
                            int* __restrict__ cursor, int n) {
    __shared__ int sums[1024];
    int t = threadIdx.x;
    int per = (n + 1023) / 1024;
    int start = t * per;
    int end = min(start + per, n);
    int s = 0;
    for (int i = start; i < end; ++i) s += cnt[i];
    sums[t] = s;
    __syncthreads();
    for (int off = 1; off < 1024; off <<= 1) {
        int v = (t >= off) ? sums[t - off] : 0;
        __syncthreads();
        sums[t] += v;
        __syncthreads();
    }
    int excl = sums[t] - s;
    int run = excl;
    for (int i = start; i < end; ++i) {
        row_ptr[i] = run;
        cursor[i]  = run;
        run += cnt[i];
    }
    if (end == n) row_ptr[n] = run;  // all threads past the end write the same total
}

// ---------------- CSR build: scatter edges by target ----------------
__global__ void build_csr_kernel(const int* __restrict__ row, const int* __restrict__ col,
                                 const float* __restrict__ dinv, int* __restrict__ cursor,
                                 int* __restrict__ csr_src, float* __restrict__ csr_w, int E) {
    int e = blockIdx.x * blockDim.x + threadIdx.x;
    if (e < E) {
        int r = row[e], c = col[e];
        int pos = atomicAdd(&cursor[c], 1);
        csr_src[pos] = r;
        csr_w[pos] = dinv[r] * dinv[c];
    }
}

// ---------------- fp32 GEMM, K=128 fixed, tiled through LDS ----------------
// Block 256 threads; thread computes ROWS_PT rows x 4 cols; W staged in K-chunks of 64.
template<int NC, int ROWS_PT, bool ADD_BIAS>
__global__ __launch_bounds__(256) void gemm_k128(
    const float* __restrict__ A, const float* __restrict__ W,
    const float* __restrict__ bias, float* __restrict__ C, int M) {
    constexpr int CID_N = NC / 4;            // threads along cols
    constexpr int RID_N = 256 / CID_N;       // thread groups along rows
    constexpr int BLOCK_ROWS = RID_N * ROWS_PT;
    __shared__ __align__(16) float Ws[64 * NC];
    __shared__ __align__(16) float hs[BLOCK_ROWS * 128];

    int tid = threadIdx.x;
    int rowBase = blockIdx.x * BLOCK_ROWS;

    // stage A rows (full K) once
    for (int i = tid * 4; i < BLOCK_ROWS * 128; i += 256 * 4) {
        int r = rowBase + (i >> 7);
        float4 v = make_float4(0.f, 0.f, 0.f, 0.f);
        if (r < M) v = *(const float4*)(A + ((size_t)r << 7) + (i & 127));
        *(float4*)&hs[i] = v;
    }

    int cid = tid % CID_N;
    int rid = tid / CID_N;
    int c0 = cid * 4;
    int r0 = rid * ROWS_PT;

    float4 acc[ROWS_PT];
#pragma unroll
    for (int r = 0; r < ROWS_PT; ++r) acc[r] = make_float4(0.f, 0.f, 0.f, 0.f);

    for (int kc = 0; kc < 128; kc += 64) {
        __syncthreads();  // protect Ws reuse + hs availability on first pass
        for (int i = tid * 4; i < 64 * NC; i += 256 * 4)
            *(float4*)&Ws[i] = *(const float4*)(W + (size_t)kc * NC + i);
        __syncthreads();
#pragma unroll
        for (int k = 0; k < 64; k += 4) {
            float4 wv[4];
#pragma unroll
            for (int kk = 0; kk < 4; ++kk)
                wv[kk] = *(const float4*)&Ws[(k + kk) * NC + c0];
#pragma unroll
            for (int r = 0; r < ROWS_PT; ++r) {
                float4 hv = *(const float4*)&hs[(r0 + r) * 128 + kc + k];
                acc[r].x = fmaf(hv.x, wv[0].x, acc[r].x);
                acc[r].y = fmaf(hv.x, wv[0].y, acc[r].y);
                acc[r].z = fmaf(hv.x, wv[0].z, acc[r].z);
                acc[r].w = fmaf(hv.x, wv[0].w, acc[r].w);
                acc[r].x = fmaf(hv.y, wv[1].x, acc[r].x);
                acc[r].y = fmaf(hv.y, wv[1].y, acc[r].y);
                acc[r].z = fmaf(hv.y, wv[1].z, acc[r].z);
                acc[r].w = fmaf(hv.y, wv[1].w, acc[r].w);
                acc[r].x = fmaf(hv.z, wv[2].x, acc[r].x);
                acc[r].y = fmaf(hv.z, wv[2].y, acc[r].y);
                acc[r].z = fmaf(hv.z, wv[2].z, acc[r].z);
                acc[r].w = fmaf(hv.z, wv[2].w, acc[r].w);
                acc[r].x = fmaf(hv.w, wv[3].x, acc[r].x);
                acc[r].y = fmaf(hv.w, wv[3].y, acc[r].y);
                acc[r].z = fmaf(hv.w, wv[3].z, acc[r].z);
                acc[r].w = fmaf(hv.w, wv[3].w, acc[r].w);
            }
        }
    }

#pragma unroll
    for (int r = 0; r < ROWS_PT; ++r) {
        int row = rowBase + r0 + r;
        if (row < M) {
            float4 o = acc[r];
            if (ADD_BIAS) {
                float4 b = *(const float4*)(bias + c0);
                o.x += b.x; o.y += b.y; o.z += b.z; o.w += b.w;
            }
            *(float4*)(C + (size_t)row * NC + c0) = o;
        }
    }
}

// ---------------- aggregation: one wave per node, float2 per lane ----------------
// out[node] = relu( sum_e w_e * h2[src_e] + dinv[node]^2 * h2[node] + bias )
__global__ __launch_bounds__(256) void agg_kernel(
    const float* __restrict__ h2, const int* __restrict__ row_ptr,
    const int* __restrict__ csr_src, const float* __restrict__ csr_w,
    const float* __restrict__ dinv, const float* __restrict__ bias,
    float* __restrict__ out, int n, int do_relu) {
    int wid = (blockIdx.x * blockDim.x + threadIdx.x) >> 6;
    int lane = threadIdx.x & 63;
    if (wid >= n) return;
    int beg = row_ptr[wid];
    int end = row_ptr[wid + 1];
    float ax = 0.f, ay = 0.f;
    for (int e = beg; e < end; ++e) {
        int src = csr_src[e];
        float w = csr_w[e];
        float2 v = *(const float2*)(h2 + ((size_t)src << 7) + (lane << 1));
        ax = fmaf(v.x, w, ax);
        ay = fmaf(v.y, w, ay);
    }
    float dv = dinv[wid];
    float sn = dv * dv;
    float2 self = *(const float2*)(h2 + ((size_t)wid << 7) + (lane << 1));
    float2 b = *(const float2*)(bias + (lane << 1));
    float ox = fmaf(self.x, sn, ax) + b.x;
    float oy = fmaf(self.y, sn, ay) + b.y;
    if (do_relu) { ox = fmaxf(ox, 0.f); oy = fmaxf(oy, 0.f); }
    *(float2*)(out + ((size_t)wid << 7) + (lane << 1)) = make_float2(ox, oy);
}

extern "C" void kernel_launch(void* const* d_in, const int* in_sizes, int n_in,
                              void* d_out, int out_size, void* d_ws, size_t ws_size,
                              hipStream_t stream) {
    const float* x  = (const float*)d_in[0];
    const int* ei   = (const int*)d_in[1];
    const float* W0 = (const float*)d_in[2];
    const float* b0 = (const float*)d_in[3];
    const float* W1 = (const float*)d_in[4];
    const float* b1 = (const float*)d_in[5];
    const float* W2 = (const float*)d_in[6];
    const float* b2 = (const float*)d_in[7];
    const float* Wl = (const float*)d_in[8];
    const float* bl = (const float*)d_in[9];
    float* out = (float*)d_out;

    const int N = N_NODES;
    const int E = in_sizes[1] / 2;
    const int* row = ei;
    const int* col = ei + E;

    // workspace carve-up (256B aligned)
    char* ws = (char*)d_ws;
    auto alloc = [&](size_t bytes) {
        char* p = ws;
        ws += (bytes + 255) & ~(size_t)255;
        return p;
    };
    int*   cnt     = (int*)alloc((size_t)N * 4);
    int*   cursor  = (int*)alloc((size_t)N * 4);
    int*   row_ptr = (int*)alloc((size_t)(N + 1) * 4);
    float* dinv    = (float*)alloc((size_t)N * 4);
    int*   csr_src = (int*)alloc((size_t)E * 4);
    float* csr_w   = (float*)alloc((size_t)E * 4);
    float* h2      = (float*)alloc((size_t)N * HID * 4);
    float* hbuf    = (float*)alloc((size_t)N * HID * 4);

    hipMemsetAsync(cnt, 0, (size_t)N * 4, stream);

    int eBlocks = (E + 255) / 256;
    int nBlocks = (N + 255) / 256;
    count_kernel<<<eBlocks, 256, 0, stream>>>(col, cnt, E);
    dinv_kernel<<<nBlocks, 256, 0, stream>>>(cnt, dinv, N);
    scan_kernel<<<1, 1024, 0, stream>>>(cnt, row_ptr, cursor, N);
    build_csr_kernel<<<eBlocks, 256, 0, stream>>>(row, col, dinv, cursor, csr_src, csr_w, E);

    const int gemmBlocks = (N + 31) / 32;       // BLOCK_ROWS = 32 for both configs
    const int aggBlocks  = (N + 3) / 4;         // 4 waves (nodes) per 256-thr block

    // layer 0
    gemm_k128<128, 4, false><<<gemmBlocks, 256, 0, stream>>>(x, W0, nullptr, h2, N);
    agg_kernel<<<aggBlocks, 256, 0, stream>>>(h2, row_ptr, csr_src, csr_w, dinv, b0, hbuf, N, 1);
    // layer 1
    gemm_k128<128, 4, false><<<gemmBlocks, 256, 0, stream>>>(hbuf, W1, nullptr, h2, N);
    agg_kernel<<<aggBlocks, 256, 0, stream>>>(h2, row_ptr, csr_src, csr_w, dinv, b1, hbuf, N, 1);
    // layer 2
    gemm_k128<128, 4, false><<<gemmBlocks, 256, 0, stream>>>(hbuf, W2, nullptr, h2, N);
    agg_kernel<<<aggBlocks, 256, 0, stream>>>(h2, row_ptr, csr_src, csr_w, dinv, b2, hbuf, N, 1);
    // classifier head
    gemm_k128<64, 2, true><<<gemmBlocks, 256, 0, stream>>>(hbuf, Wl, bl, out, N);
}

// Round 2
// 497.632 us; speedup vs baseline: 1.2351x; 1.2351x over previous
//
#include <hip/hip_runtime.h>
#include <hip/hip_bf16.h>

#define N_NODES 50000
#define HID 128
#define CLS 64

// ---------------- degree count ----------------
__global__ void count_kernel(const int* __restrict__ col, int* __restrict__ cnt, int E) {
    int e = blockIdx.x * blockDim.x + threadIdx.x;
    if (e < E) atomicAdd(&cnt[col[e]], 1);
}

// ---------------- dinv = rsqrt(deg+1) ----------------
__global__ void dinv_kernel(const int* __restrict__ cnt, float* __restrict__ dinv, int n) {
    int i = blockIdx.x * blockDim.x + threadIdx.x;
    if (i < n) dinv[i] = rsqrtf((float)cnt[i] + 1.0f);
}

// ---------------- multi-block exclusive scan, phase 1: per-block sums ----------------
__global__ __launch_bounds__(256) void block_sum_kernel(const int* __restrict__ cnt,
                                                        int* __restrict__ bsum, int n) {
    int i = blockIdx.x * 256 + threadIdx.x;
    int v = (i < n) ? cnt[i] : 0;
#pragma unroll
    for (int off = 32; off; off >>= 1) v += __shfl_down(v, off, 64);
    __shared__ int ws[4];
    if ((threadIdx.x & 63) == 0) ws[threadIdx.x >> 6] = v;
    __syncthreads();
    if (threadIdx.x == 0) bsum[blockIdx.x] = ws[0] + ws[1] + ws[2] + ws[3];
}

// ---------------- phase 2: exclusive scan of block sums (nb <= 256) ----------------
__global__ __launch_bounds__(256) void scan_bsum_kernel(int* __restrict__ bsum, int nb) {
    __shared__ int s[256];
    int t = threadIdx.x;
    int v = (t < nb) ? bsum[t] : 0;
    s[t] = v;
    __syncthreads();
#pragma unroll
    for (int off = 1; off < 256; off <<= 1) {
        int u = (t >= off) ? s[t - off] : 0;
        __syncthreads();
        s[t] += u;
        __syncthreads();
    }
    if (t < nb) bsum[t] = s[t] - v;  // exclusive
}

// ---------------- phase 3: per-block scan + global offset ----------------
__global__ __launch_bounds__(256) void scan_final_kernel(const int* __restrict__ cnt,
                                                         const int* __restrict__ bsum_excl,
                                                         int* __restrict__ row_ptr,
                                                         int* __restrict__ cursor, int n) {
    __shared__ int s[256];
    int t = threadIdx.x;
    int i = blockIdx.x * 256 + t;
    int v = (i < n) ? cnt[i] : 0;
    s[t] = v;
    __syncthreads();
#pragma unroll
    for (int off = 1; off < 256; off <<= 1) {
        int u = (t >= off) ? s[t - off] : 0;
        __syncthreads();
        s[t] += u;
        __syncthreads();
    }
    int excl = bsum_excl[blockIdx.x] + s[t] - v;
    if (i < n) {
        row_ptr[i] = excl;
        cursor[i] = excl;
        if (i == n - 1) row_ptr[n] = excl + v;
    }
}

// ---------------- CSR build: scatter edges by target ----------------
__global__ void build_csr_kernel(const int* __restrict__ row, const int* __restrict__ col,
                                 const float* __restrict__ dinv, int* __restrict__ cursor,
                                 int* __restrict__ csr_src, float* __restrict__ csr_w, int E) {
    int e = blockIdx.x * blockDim.x + threadIdx.x;
    if (e < E) {
        int r = row[e], c = col[e];
        int pos = atomicAdd(&cursor[c], 1);
        csr_src[pos] = r;
        csr_w[pos] = dinv[r] * dinv[c];
    }
}

// ---------------- fp32 GEMM, K=128 fixed, tiled through LDS ----------------
// Block 256 threads; thread computes ROWS_PT rows x 4 cols; A and W staged in
// K-chunks of 64 (LDS: 64*NC*4 + BLOCK_ROWS*64*4 bytes).
template<int NC, int ROWS_PT, bool ADD_BIAS>
__global__ __launch_bounds__(256) void gemm_k128(
    const float* __restrict__ A, const float* __restrict__ W,
    const float* __restrict__ bias, float* __restrict__ C, int M) {
    constexpr int CID_N = NC / 4;            // threads along cols
    constexpr int RID_N = 256 / CID_N;       // thread groups along rows
    constexpr int BLOCK_ROWS = RID_N * ROWS_PT;
    __shared__ __align__(16) float Ws[64 * NC];
    __shared__ __align__(16) float hs[BLOCK_ROWS * 64];

    int tid = threadIdx.x;
    int rowBase = blockIdx.x * BLOCK_ROWS;

    int cid = tid % CID_N;
    int rid = tid / CID_N;
    int c0 = cid * 4;
    int r0 = rid * ROWS_PT;

    float4 acc[ROWS_PT];
#pragma unroll
    for (int r = 0; r < ROWS_PT; ++r) acc[r] = make_float4(0.f, 0.f, 0.f, 0.f);

    for (int kc = 0; kc < 128; kc += 64) {
        __syncthreads();
        // stage W chunk: rows kc..kc+64 of W[K][NC]
        for (int i = tid * 4; i < 64 * NC; i += 256 * 4)
            *(float4*)&Ws[i] = *(const float4*)(W + (size_t)kc * NC + i);
        // stage A chunk: BLOCK_ROWS rows x 64 k-cols
        for (int i = tid * 4; i < BLOCK_ROWS * 64; i += 256 * 4) {
            int r = rowBase + (i >> 6);
            float4 v = make_float4(0.f, 0.f, 0.f, 0.f);
            if (r < M) v = *(const float4*)(A + ((size_t)r << 7) + kc + (i & 63));
            *(float4*)&hs[i] = v;
        }
        __syncthreads();
#pragma unroll
        for (int k = 0; k < 64; k += 4) {
            float4 wv[4];
#pragma unroll
            for (int kk = 0; kk < 4; ++kk)
                wv[kk] = *(const float4*)&Ws[(k + kk) * NC + c0];
#pragma unroll
            for (int r = 0; r < ROWS_PT; ++r) {
                float4 hv = *(const float4*)&hs[(r0 + r) * 64 + k];
                acc[r].x = fmaf(hv.x, wv[0].x, acc[r].x);
                acc[r].y = fmaf(hv.x, wv[0].y, acc[r].y);
                acc[r].z = fmaf(hv.x, wv[0].z, acc[r].z);
                acc[r].w = fmaf(hv.x, wv[0].w, acc[r].w);
                acc[r].x = fmaf(hv.y, wv[1].x, acc[r].x);
                acc[r].y = fmaf(hv.y, wv[1].y, acc[r].y);
                acc[r].z = fmaf(hv.y, wv[1].z, acc[r].z);
                acc[r].w = fmaf(hv.y, wv[1].w, acc[r].w);
                acc[r].x = fmaf(hv.z, wv[2].x, acc[r].x);
                acc[r].y = fmaf(hv.z, wv[2].y, acc[r].y);
                acc[r].z = fmaf(hv.z, wv[2].z, acc[r].z);
                acc[r].w = fmaf(hv.z, wv[2].w, acc[r].w);
                acc[r].x = fmaf(hv.w, wv[3].x, acc[r].x);
                acc[r].y = fmaf(hv.w, wv[3].y, acc[r].y);
                acc[r].z = fmaf(hv.w, wv[3].z, acc[r].z);
                acc[r].w = fmaf(hv.w, wv[3].w, acc[r].w);
            }
        }
    }

#pragma unroll
    for (int r = 0; r < ROWS_PT; ++r) {
        int row = rowBase + r0 + r;
        if (row < M) {
            float4 o = acc[r];
            if (ADD_BIAS) {
                float4 b = *(const float4*)(bias + c0);
                o.x += b.x; o.y += b.y; o.z += b.z; o.w += b.w;
            }
            *(float4*)(C + (size_t)row * NC + c0) = o;
        }
    }
}

// ---------------- aggregation: one wave per node, float2 per lane ----------------
// out[node] = relu( sum_e w_e * h2[src_e] + dinv[node]^2 * h2[node] + bias )
__global__ __launch_bounds__(256) void agg_kernel(
    const float* __restrict__ h2, const int* __restrict__ row_ptr,
    const int* __restrict__ csr_src, const float* __restrict__ csr_w,
    const float* __restrict__ dinv, const float* __restrict__ bias,
    float* __restrict__ out, int n, int do_relu) {
    int wid = (blockIdx.x * blockDim.x + threadIdx.x) >> 6;
    int lane = threadIdx.x & 63;
    if (wid >= n) return;
    int beg = row_ptr[wid];
    int end = row_ptr[wid + 1];
    float ax = 0.f, ay = 0.f;
    for (int e = beg; e < end; ++e) {
        int src = csr_src[e];
        float w = csr_w[e];
        float2 v = *(const float2*)(h2 + ((size_t)src << 7) + (lane << 1));
        ax = fmaf(v.x, w, ax);
        ay = fmaf(v.y, w, ay);
    }
    float dv = dinv[wid];
    float sn = dv * dv;
    float2 self = *(const float2*)(h2 + ((size_t)wid << 7) + (lane << 1));
    float2 b = *(const float2*)(bias + (lane << 1));
    float ox = fmaf(self.x, sn, ax) + b.x;
    float oy = fmaf(self.y, sn, ay) + b.y;
    if (do_relu) { ox = fmaxf(ox, 0.f); oy = fmaxf(oy, 0.f); }
    *(float2*)(out + ((size_t)wid << 7) + (lane << 1)) = make_float2(ox, oy);
}

extern "C" void kernel_launch(void* const* d_in, const int* in_sizes, int n_in,
                              void* d_out, int out_size, void* d_ws, size_t ws_size,
                              hipStream_t stream) {
    const float* x  = (const float*)d_in[0];
    const int* ei   = (const int*)d_in[1];
    const float* W0 = (const float*)d_in[2];
    const float* b0 = (const float*)d_in[3];
    const float* W1 = (const float*)d_in[4];
    const float* b1 = (const float*)d_in[5];
    const float* W2 = (const float*)d_in[6];
    const float* b2 = (const float*)d_in[7];
    const float* Wl = (const float*)d_in[8];
    const float* bl = (const float*)d_in[9];
    float* out = (float*)d_out;

    const int N = N_NODES;
    const int E = in_sizes[1] / 2;
    const int* row = ei;
    const int* col = ei + E;

    // workspace carve-up (256B aligned)
    char* ws = (char*)d_ws;
    auto alloc = [&](size_t bytes) {
        char* p = ws;
        ws += (bytes + 255) & ~(size_t)255;
        return p;
    };
    int*   cnt     = (int*)alloc((size_t)N * 4);
    int*   cursor  = (int*)alloc((size_t)N * 4);
    int*   row_ptr = (int*)alloc((size_t)(N + 1) * 4);
    float* dinv    = (float*)alloc((size_t)N * 4);
    int*   csr_src = (int*)alloc((size_t)E * 4);
    float* csr_w   = (float*)alloc((size_t)E * 4);
    float* h2      = (float*)alloc((size_t)N * HID * 4);
    float* hbuf    = (float*)alloc((size_t)N * HID * 4);
    int*   bsum    = (int*)alloc((size_t)256 * 4);

    hipMemsetAsync(cnt, 0, (size_t)N * 4, stream);

    int eBlocks = (E + 255) / 256;
    int nBlocks = (N + 255) / 256;
    count_kernel<<<eBlocks, 256, 0, stream>>>(col, cnt, E);
    dinv_kernel<<<nBlocks, 256, 0, stream>>>(cnt, dinv, N);
    block_sum_kernel<<<nBlocks, 256, 0, stream>>>(cnt, bsum, N);
    scan_bsum_kernel<<<1, 256, 0, stream>>>(bsum, nBlocks);
    scan_final_kernel<<<nBlocks, 256, 0, stream>>>(cnt, bsum, row_ptr, cursor, N);
    build_csr_kernel<<<eBlocks, 256, 0, stream>>>(row, col, dinv, cursor, csr_src, csr_w, E);

    const int gemmBlocks = (N + 63) / 64;  // BLOCK_ROWS = 64 for both configs below
    const int aggBlocks  = (N + 3) / 4;    // 4 waves (nodes) per 256-thr block

    // layer 0
    gemm_k128<128, 8, false><<<gemmBlocks, 256, 0, stream>>>(x, W0, nullptr, h2, N);
    agg_kernel<<<aggBlocks, 256, 0, stream>>>(h2, row_ptr, csr_src, csr_w, dinv, b0, hbuf, N, 1);
    // layer 1
    gemm_k128<128, 8, false><<<gemmBlocks, 256, 0, stream>>>(hbuf, W1, nullptr, h2, N);
    agg_kernel<<<aggBlocks, 256, 0, stream>>>(h2, row_ptr, csr_src, csr_w, dinv, b1, hbuf, N, 1);
    // layer 2
    gemm_k128<128, 8, false><<<gemmBlocks, 256, 0, stream>>>(hbuf, W2, nullptr, h2, N);
    agg_kernel<<<aggBlocks, 256, 0, stream>>>(h2, row_ptr, csr_src, csr_w, dinv, b2, hbuf, N, 1);
    // classifier head
    gemm_k128<64, 4, true><<<gemmBlocks, 256, 0, stream>>>(hbuf, Wl, bl, out, N);
}

// Round 3
// 449.185 us; speedup vs baseline: 1.3683x; 1.1079x over previous
//
#include <hip/hip_runtime.h>
#include <hip/hip_bf16.h>

#define N_NODES 50000
#define HID 128
#define CLS 64

typedef __attribute__((ext_vector_type(8))) short bf16x8;
typedef __attribute__((ext_vector_type(4))) float f32x4;

__device__ __forceinline__ unsigned short f2bf_rne(float f) {
    unsigned int u = __float_as_uint(f);
    unsigned int r = (u + 0x7FFFu + ((u >> 16) & 1u)) >> 16;
    return (unsigned short)r;
}
__device__ __forceinline__ float bf2f(unsigned short h) {
    return __uint_as_float(((unsigned int)h) << 16);
}

// ---------------- degree count ----------------
__global__ void count_kernel(const int* __restrict__ col, int* __restrict__ cnt, int E) {
    int e = blockIdx.x * blockDim.x + threadIdx.x;
    if (e < E) atomicAdd(&cnt[col[e]], 1);
}

// ---------------- dinv = rsqrt(deg+1) ----------------
__global__ void dinv_kernel(const int* __restrict__ cnt, float* __restrict__ dinv, int n) {
    int i = blockIdx.x * blockDim.x + threadIdx.x;
    if (i < n) dinv[i] = rsqrtf((float)cnt[i] + 1.0f);
}

// ---------------- multi-block exclusive scan ----------------
__global__ __launch_bounds__(256) void block_sum_kernel(const int* __restrict__ cnt,
                                                        int* __restrict__ bsum, int n) {
    int i = blockIdx.x * 256 + threadIdx.x;
    int v = (i < n) ? cnt[i] : 0;
#pragma unroll
    for (int off = 32; off; off >>= 1) v += __shfl_down(v, off, 64);
    __shared__ int ws[4];
    if ((threadIdx.x & 63) == 0) ws[threadIdx.x >> 6] = v;
    __syncthreads();
    if (threadIdx.x == 0) bsum[blockIdx.x] = ws[0] + ws[1] + ws[2] + ws[3];
}

__global__ __launch_bounds__(256) void scan_bsum_kernel(int* __restrict__ bsum, int nb) {
    __shared__ int s[256];
    int t = threadIdx.x;
    int v = (t < nb) ? bsum[t] : 0;
    s[t] = v;
    __syncthreads();
#pragma unroll
    for (int off = 1; off < 256; off <<= 1) {
        int u = (t >= off) ? s[t - off] : 0;
        __syncthreads();
        s[t] += u;
        __syncthreads();
    }
    if (t < nb) bsum[t] = s[t] - v;  // exclusive
}

__global__ __launch_bounds__(256) void scan_final_kernel(const int* __restrict__ cnt,
                                                         const int* __restrict__ bsum_excl,
                                                         int* __restrict__ row_ptr,
                                                         int* __restrict__ cursor, int n) {
    __shared__ int s[256];
    int t = threadIdx.x;
    int i = blockIdx.x * 256 + t;
    int v = (i < n) ? cnt[i] : 0;
    s[t] = v;
    __syncthreads();
#pragma unroll
    for (int off = 1; off < 256; off <<= 1) {
        int u = (t >= off) ? s[t - off] : 0;
        __syncthreads();
        s[t] += u;
        __syncthreads();
    }
    int excl = bsum_excl[blockIdx.x] + s[t] - v;
    if (i < n) {
        row_ptr[i] = excl;
        cursor[i] = excl;
        if (i == n - 1) row_ptr[n] = excl + v;
    }
}

// ---------------- CSR build ----------------
__global__ void build_csr_kernel(const int* __restrict__ row, const int* __restrict__ col,
                                 const float* __restrict__ dinv, int* __restrict__ cursor,
                                 int* __restrict__ csr_src, float* __restrict__ csr_w, int E) {
    int e = blockIdx.x * blockDim.x + threadIdx.x;
    if (e < E) {
        int r = row[e], c = col[e];
        int pos = atomicAdd(&cursor[c], 1);
        csr_src[pos] = r;
        csr_w[pos] = dinv[r] * dinv[c];
    }
}

// ---------------- split fp32 -> (hi, lo) bf16, vectorized x4 ----------------
__global__ __launch_bounds__(256) void split_cast_kernel(
    const float* __restrict__ in, unsigned short* __restrict__ hi,
    unsigned short* __restrict__ lo, int n4) {
    int i = blockIdx.x * 256 + threadIdx.x;
    if (i >= n4) return;
    float4 v = ((const float4*)in)[i];
    ushort4 h, l;
    h.x = f2bf_rne(v.x); l.x = f2bf_rne(v.x - bf2f(h.x));
    h.y = f2bf_rne(v.y); l.y = f2bf_rne(v.y - bf2f(h.y));
    h.z = f2bf_rne(v.z); l.z = f2bf_rne(v.z - bf2f(h.z));
    h.w = f2bf_rne(v.w); l.w = f2bf_rne(v.w - bf2f(h.w));
    ((ushort4*)hi)[i] = h;
    ((ushort4*)lo)[i] = l;
}

// ---------------- W [K=128, NCdim] fp32 -> transposed [n][k] hi/lo bf16 ----------------
__global__ __launch_bounds__(256) void wsplit_kernel(
    const float* __restrict__ W, int NCdim,
    unsigned short* __restrict__ Wh, unsigned short* __restrict__ Wl, int total) {
    int idx = blockIdx.x * 256 + threadIdx.x;  // idx = n*128 + k
    if (idx >= total) return;
    int n = idx >> 7;
    int k = idx & 127;
    float v = W[(size_t)k * NCdim + n];
    unsigned short h = f2bf_rne(v);
    Wh[idx] = h;
    Wl[idx] = f2bf_rne(v - bf2f(h));
}

// ---------------- split-bf16 MFMA GEMM: C = A @ W (+bias), K=128 ----------------
// A given as hi/lo bf16 [M,128] k-contiguous; W as hi/lo bf16 [NC,128] (n-major,
// k-contiguous). Per wave: one 16-row stripe x full NC. No LDS.
template<int NC, bool ADD_BIAS>
__global__ __launch_bounds__(256) void mfma_gemm_split(
    const unsigned short* __restrict__ Ah, const unsigned short* __restrict__ Al,
    const unsigned short* __restrict__ Bh, const unsigned short* __restrict__ Bl,
    const float* __restrict__ bias, float* __restrict__ C, int M) {
    constexpr int NT = NC / 16;
    int lane = threadIdx.x & 63;
    int rowTile = blockIdx.x * 4 + (threadIdx.x >> 6);
    int m0 = rowTile << 4;
    if (m0 >= M) return;
    int mr = lane & 15;
    int kq = (lane >> 4) << 3;  // 0,8,16,24

    const unsigned short* ah = Ah + (size_t)(m0 + mr) * 128 + kq;
    const unsigned short* al = Al + (size_t)(m0 + mr) * 128 + kq;
    const unsigned short* bh = Bh + (size_t)mr * 128 + kq;
    const unsigned short* bl = Bl + (size_t)mr * 128 + kq;

    f32x4 acc[NT];
#pragma unroll
    for (int t = 0; t < NT; ++t) acc[t] = (f32x4){0.f, 0.f, 0.f, 0.f};

#pragma unroll
    for (int kc = 0; kc < 128; kc += 32) {
        bf16x8 a_h = *(const bf16x8*)(ah + kc);
        bf16x8 a_l = *(const bf16x8*)(al + kc);
#pragma unroll
        for (int t = 0; t < NT; ++t) {
            bf16x8 b_h = *(const bf16x8*)(bh + (size_t)t * 16 * 128 + kc);
            bf16x8 b_l = *(const bf16x8*)(bl + (size_t)t * 16 * 128 + kc);
            acc[t] = __builtin_amdgcn_mfma_f32_16x16x32_bf16(a_h, b_h, acc[t], 0, 0, 0);
            acc[t] = __builtin_amdgcn_mfma_f32_16x16x32_bf16(a_l, b_h, acc[t], 0, 0, 0);
            acc[t] = __builtin_amdgcn_mfma_f32_16x16x32_bf16(a_h, b_l, acc[t], 0, 0, 0);
        }
    }

    // C/D layout: col = lane&15, row = (lane>>4)*4 + reg
    int r0 = m0 + ((lane >> 4) << 2);
    int cc = lane & 15;
#pragma unroll
    for (int t = 0; t < NT; ++t) {
        float bsv = ADD_BIAS ? bias[t * 16 + cc] : 0.f;
#pragma unroll
        for (int r = 0; r < 4; ++r)
            C[(size_t)(r0 + r) * NC + t * 16 + cc] = acc[t][r] + bsv;
    }
}

// ---------------- aggregation: one wave per node, shfl-broadcast edge metadata ----
// out = relu( sum_e w_e*h2[src_e] + dinv^2*h2[node] + bias ), written as hi/lo bf16
__global__ __launch_bounds__(256) void agg_kernel(
    const float* __restrict__ h2, const int* __restrict__ row_ptr,
    const int* __restrict__ csr_src, const float* __restrict__ csr_w,
    const float* __restrict__ dinv, const float* __restrict__ bias,
    unsigned short* __restrict__ out_hi, unsigned short* __restrict__ out_lo, int n) {
    int wid = (blockIdx.x * 256 + threadIdx.x) >> 6;
    int lane = threadIdx.x & 63;
    if (wid >= n) return;
    int beg = row_ptr[wid];
    int end = row_ptr[wid + 1];
    float ax = 0.f, ay = 0.f;
    int loff = lane << 1;
    for (int base = beg; base < end; base += 64) {
        int cnt = end - base;
        if (cnt > 64) cnt = 64;
        int msrc = 0;
        float mw = 0.f;
        if (lane < cnt) {
            msrc = csr_src[base + lane];
            mw = csr_w[base + lane];
        }
        int j = 0;
        for (; j + 4 <= cnt; j += 4) {
            int s0 = __shfl(msrc, j), s1 = __shfl(msrc, j + 1);
            int s2 = __shfl(msrc, j + 2), s3 = __shfl(msrc, j + 3);
            float w0 = __shfl(mw, j), w1 = __shfl(mw, j + 1);
            float w2 = __shfl(mw, j + 2), w3 = __shfl(mw, j + 3);
            float2 v0 = *(const float2*)(h2 + ((size_t)s0 << 7) + loff);
            float2 v1 = *(const float2*)(h2 + ((size_t)s1 << 7) + loff);
            float2 v2 = *(const float2*)(h2 + ((size_t)s2 << 7) + loff);
            float2 v3 = *(const float2*)(h2 + ((size_t)s3 << 7) + loff);
            ax = fmaf(v0.x, w0, ax); ay = fmaf(v0.y, w0, ay);
            ax = fmaf(v1.x, w1, ax); ay = fmaf(v1.y, w1, ay);
            ax = fmaf(v2.x, w2, ax); ay = fmaf(v2.y, w2, ay);
            ax = fmaf(v3.x, w3, ax); ay = fmaf(v3.y, w3, ay);
        }
        for (; j < cnt; ++j) {
            int s = __shfl(msrc, j);
            float w = __shfl(mw, j);
            float2 v = *(const float2*)(h2 + ((size_t)s << 7) + loff);
            ax = fmaf(v.x, w, ax); ay = fmaf(v.y, w, ay);
        }
    }
    float dv = dinv[wid];
    float sn = dv * dv;
    float2 self = *(const float2*)(h2 + ((size_t)wid << 7) + loff);
    float2 b = *(const float2*)(bias + loff);
    float ox = fmaxf(fmaf(self.x, sn, ax) + b.x, 0.f);
    float oy = fmaxf(fmaf(self.y, sn, ay) + b.y, 0.f);
    unsigned short hx = f2bf_rne(ox), hy = f2bf_rne(oy);
    ushort2 hv, lv;
    hv.x = hx; hv.y = hy;
    lv.x = f2bf_rne(ox - bf2f(hx));
    lv.y = f2bf_rne(oy - bf2f(hy));
    size_t o = ((size_t)wid << 7) + loff;
    *(ushort2*)(out_hi + o) = hv;
    *(ushort2*)(out_lo + o) = lv;
}

extern "C" void kernel_launch(void* const* d_in, const int* in_sizes, int n_in,
                              void* d_out, int out_size, void* d_ws, size_t ws_size,
                              hipStream_t stream) {
    const float* x  = (const float*)d_in[0];
    const int* ei   = (const int*)d_in[1];
    const float* W0 = (const float*)d_in[2];
    const float* b0 = (const float*)d_in[3];
    const float* W1 = (const float*)d_in[4];
    const float* b1 = (const float*)d_in[5];
    const float* W2 = (const float*)d_in[6];
    const float* b2 = (const float*)d_in[7];
    const float* Wl = (const float*)d_in[8];
    const float* bl = (const float*)d_in[9];
    float* out = (float*)d_out;

    const int N = N_NODES;
    const int E = in_sizes[1] / 2;
    const int* row = ei;
    const int* col = ei + E;

    char* ws = (char*)d_ws;
    auto alloc = [&](size_t bytes) {
        char* p = ws;
        ws += (bytes + 255) & ~(size_t)255;
        return p;
    };
    int*   cnt     = (int*)alloc((size_t)N * 4);
    int*   cursor  = (int*)alloc((size_t)N * 4);
    int*   row_ptr = (int*)alloc((size_t)(N + 1) * 4);
    float* dinv    = (float*)alloc((size_t)N * 4);
    int*   csr_src = (int*)alloc((size_t)E * 4);
    float* csr_w   = (float*)alloc((size_t)E * 4);
    float* h2      = (float*)alloc((size_t)N * HID * 4);     // GEMM output (fp32)
    unsigned short* h_hi = (unsigned short*)alloc((size_t)N * HID * 2);
    unsigned short* h_lo = (unsigned short*)alloc((size_t)N * HID * 2);
    unsigned short* Wt_hi[4];
    unsigned short* Wt_lo[4];
    for (int i = 0; i < 3; ++i) {
        Wt_hi[i] = (unsigned short*)alloc((size_t)HID * HID * 2);
        Wt_lo[i] = (unsigned short*)alloc((size_t)HID * HID * 2);
    }
    Wt_hi[3] = (unsigned short*)alloc((size_t)CLS * HID * 2);
    Wt_lo[3] = (unsigned short*)alloc((size_t)CLS * HID * 2);
    int* bsum = (int*)alloc((size_t)256 * 4);

    hipMemsetAsync(cnt, 0, (size_t)N * 4, stream);

    int eBlocks = (E + 255) / 256;
    int nBlocks = (N + 255) / 256;
    count_kernel<<<eBlocks, 256, 0, stream>>>(col, cnt, E);
    dinv_kernel<<<nBlocks, 256, 0, stream>>>(cnt, dinv, N);
    block_sum_kernel<<<nBlocks, 256, 0, stream>>>(cnt, bsum, N);
    scan_bsum_kernel<<<1, 256, 0, stream>>>(bsum, nBlocks);
    scan_final_kernel<<<nBlocks, 256, 0, stream>>>(cnt, bsum, row_ptr, cursor, N);
    build_csr_kernel<<<eBlocks, 256, 0, stream>>>(row, col, dinv, cursor, csr_src, csr_w, E);

    // input split + weight transpose-splits (independent of CSR chain)
    int n4 = N * HID / 4;
    split_cast_kernel<<<(n4 + 255) / 256, 256, 0, stream>>>(x, h_hi, h_lo, n4);
    wsplit_kernel<<<(HID * HID + 255) / 256, 256, 0, stream>>>(W0, HID, Wt_hi[0], Wt_lo[0], HID * HID);
    wsplit_kernel<<<(HID * HID + 255) / 256, 256, 0, stream>>>(W1, HID, Wt_hi[1], Wt_lo[1], HID * HID);
    wsplit_kernel<<<(HID * HID + 255) / 256, 256, 0, stream>>>(W2, HID, Wt_hi[2], Wt_lo[2], HID * HID);
    wsplit_kernel<<<(CLS * HID + 255) / 256, 256, 0, stream>>>(Wl, CLS, Wt_hi[3], Wt_lo[3], CLS * HID);

    const int gemmBlocks = (N / 16 + 3) / 4 + 1;  // 3125 row-tiles, 4 waves/block
    const int aggBlocks  = (N + 3) / 4;

    // layer 0
    mfma_gemm_split<128, false><<<gemmBlocks, 256, 0, stream>>>(h_hi, h_lo, Wt_hi[0], Wt_lo[0], nullptr, h2, N);
    agg_kernel<<<aggBlocks, 256, 0, stream>>>(h2, row_ptr, csr_src, csr_w, dinv, b0, h_hi, h_lo, N);
    // layer 1
    mfma_gemm_split<128, false><<<gemmBlocks, 256, 0, stream>>>(h_hi, h_lo, Wt_hi[1], Wt_lo[1], nullptr, h2, N);
    agg_kernel<<<aggBlocks, 256, 0, stream>>>(h2, row_ptr, csr_src, csr_w, dinv, b1, h_hi, h_lo, N);
    // layer 2
    mfma_gemm_split<128, false><<<gemmBlocks, 256, 0, stream>>>(h_hi, h_lo, Wt_hi[2], Wt_lo[2], nullptr, h2, N);
    agg_kernel<<<aggBlocks, 256, 0, stream>>>(h2, row_ptr, csr_src, csr_w, dinv, b2, h_hi, h_lo, N);
    // classifier head
    mfma_gemm_split<64, true><<<gemmBlocks, 256, 0, stream>>>(h_hi, h_lo, Wt_hi[3], Wt_lo[3], bl, out, N);
}

// Round 4
// 401.515 us; speedup vs baseline: 1.5308x; 1.1187x over previous
//
#include <hip/hip_runtime.h>
#include <hip/hip_bf16.h>
#include <hip/hip_fp16.h>

#define N_NODES 50000
#define HID 128
#define CLS 64

typedef __attribute__((ext_vector_type(8))) short bf16x8;
typedef __attribute__((ext_vector_type(4))) float f32x4;

__device__ __forceinline__ unsigned short f2bf_rne(float f) {
    unsigned int u = __float_as_uint(f);
    unsigned int r = (u + 0x7FFFu + ((u >> 16) & 1u)) >> 16;
    return (unsigned short)r;
}
__device__ __forceinline__ float bf2f(unsigned short h) {
    return __uint_as_float(((unsigned int)h) << 16);
}

// ---------------- degree count ----------------
__global__ void count_kernel(const int* __restrict__ col, int* __restrict__ cnt, int E) {
    int e = blockIdx.x * blockDim.x + threadIdx.x;
    if (e < E) atomicAdd(&cnt[col[e]], 1);
}

// ---------------- dinv = rsqrt(deg+1) ----------------
__global__ void dinv_kernel(const int* __restrict__ cnt, float* __restrict__ dinv, int n) {
    int i = blockIdx.x * blockDim.x + threadIdx.x;
    if (i < n) dinv[i] = rsqrtf((float)cnt[i] + 1.0f);
}

// ---------------- multi-block exclusive scan ----------------
__global__ __launch_bounds__(256) void block_sum_kernel(const int* __restrict__ cnt,
                                                        int* __restrict__ bsum, int n) {
    int i = blockIdx.x * 256 + threadIdx.x;
    int v = (i < n) ? cnt[i] : 0;
#pragma unroll
    for (int off = 32; off; off >>= 1) v += __shfl_down(v, off, 64);
    __shared__ int ws[4];
    if ((threadIdx.x & 63) == 0) ws[threadIdx.x >> 6] = v;
    __syncthreads();
    if (threadIdx.x == 0) bsum[blockIdx.x] = ws[0] + ws[1] + ws[2] + ws[3];
}

__global__ __launch_bounds__(256) void scan_bsum_kernel(int* __restrict__ bsum, int nb) {
    __shared__ int s[256];
    int t = threadIdx.x;
    int v = (t < nb) ? bsum[t] : 0;
    s[t] = v;
    __syncthreads();
#pragma unroll
    for (int off = 1; off < 256; off <<= 1) {
        int u = (t >= off) ? s[t - off] : 0;
        __syncthreads();
        s[t] += u;
        __syncthreads();
    }
    if (t < nb) bsum[t] = s[t] - v;  // exclusive
}

__global__ __launch_bounds__(256) void scan_final_kernel(const int* __restrict__ cnt,
                                                         const int* __restrict__ bsum_excl,
                                                         int* __restrict__ row_ptr,
                                                         int* __restrict__ cursor, int n) {
    __shared__ int s[256];
    int t = threadIdx.x;
    int i = blockIdx.x * 256 + t;
    int v = (i < n) ? cnt[i] : 0;
    s[t] = v;
    __syncthreads();
#pragma unroll
    for (int off = 1; off < 256; off <<= 1) {
        int u = (t >= off) ? s[t - off] : 0;
        __syncthreads();
        s[t] += u;
        __syncthreads();
    }
    int excl = bsum_excl[blockIdx.x] + s[t] - v;
    if (i < n) {
        row_ptr[i] = excl;
        cursor[i] = excl;
        if (i == n - 1) row_ptr[n] = excl + v;
    }
}

// ---------------- CSR build: single 4B scatter per edge ----------------
__global__ void build_csr_kernel(const int* __restrict__ row, const int* __restrict__ col,
                                 int* __restrict__ cursor, int* __restrict__ csr_src, int E) {
    int e = blockIdx.x * blockDim.x + threadIdx.x;
    if (e < E) {
        int r = row[e], c = col[e];
        int pos = atomicAdd(&cursor[c], 1);
        csr_src[pos] = r;
    }
}

// ---------------- split fp32 -> (hi, lo) bf16, vectorized x4 ----------------
__global__ __launch_bounds__(256) void split_cast_kernel(
    const float* __restrict__ in, unsigned short* __restrict__ hi,
    unsigned short* __restrict__ lo, int n4) {
    int i = blockIdx.x * 256 + threadIdx.x;
    if (i >= n4) return;
    float4 v = ((const float4*)in)[i];
    ushort4 h, l;
    h.x = f2bf_rne(v.x); l.x = f2bf_rne(v.x - bf2f(h.x));
    h.y = f2bf_rne(v.y); l.y = f2bf_rne(v.y - bf2f(h.y));
    h.z = f2bf_rne(v.z); l.z = f2bf_rne(v.z - bf2f(h.z));
    h.w = f2bf_rne(v.w); l.w = f2bf_rne(v.w - bf2f(h.w));
    ((ushort4*)hi)[i] = h;
    ((ushort4*)lo)[i] = l;
}

// ---------------- W [K=128, NCdim] fp32 -> transposed [n][k] hi/lo bf16 ----------------
__global__ __launch_bounds__(256) void wsplit_kernel(
    const float* __restrict__ W, int NCdim,
    unsigned short* __restrict__ Wh, unsigned short* __restrict__ Wl, int total) {
    int idx = blockIdx.x * 256 + threadIdx.x;  // idx = n*128 + k
    if (idx >= total) return;
    int n = idx >> 7;
    int k = idx & 127;
    float v = W[(size_t)k * NCdim + n];
    unsigned short h = f2bf_rne(v);
    Wh[idx] = h;
    Wl[idx] = f2bf_rne(v - bf2f(h));
}

// ---------------- split-bf16 MFMA GEMM: C = A @ W (+bias), K=128 ----------------
// A hi/lo bf16 [M,128] k-contiguous; W hi/lo bf16 [NC,128] n-major k-contiguous.
// HALF_OUT: store fp16 (for the aggregation gather); else fp32.
template<int NC, bool ADD_BIAS, bool HALF_OUT>
__global__ __launch_bounds__(256) void mfma_gemm_split(
    const unsigned short* __restrict__ Ah, const unsigned short* __restrict__ Al,
    const unsigned short* __restrict__ Bh, const unsigned short* __restrict__ Bl,
    const float* __restrict__ bias, void* __restrict__ Cv, int M) {
    constexpr int NT = NC / 16;
    int lane = threadIdx.x & 63;
    int rowTile = blockIdx.x * 4 + (threadIdx.x >> 6);
    int m0 = rowTile << 4;
    if (m0 >= M) return;
    int mr = lane & 15;
    int kq = (lane >> 4) << 3;  // 0,8,16,24

    const unsigned short* ah = Ah + (size_t)(m0 + mr) * 128 + kq;
    const unsigned short* al = Al + (size_t)(m0 + mr) * 128 + kq;
    const unsigned short* bh = Bh + (size_t)mr * 128 + kq;
    const unsigned short* bl = Bl + (size_t)mr * 128 + kq;

    f32x4 acc[NT];
#pragma unroll
    for (int t = 0; t < NT; ++t) acc[t] = (f32x4){0.f, 0.f, 0.f, 0.f};

#pragma unroll
    for (int kc = 0; kc < 128; kc += 32) {
        bf16x8 a_h = *(const bf16x8*)(ah + kc);
        bf16x8 a_l = *(const bf16x8*)(al + kc);
#pragma unroll
        for (int t = 0; t < NT; ++t) {
            bf16x8 b_h = *(const bf16x8*)(bh + (size_t)t * 16 * 128 + kc);
            bf16x8 b_l = *(const bf16x8*)(bl + (size_t)t * 16 * 128 + kc);
            acc[t] = __builtin_amdgcn_mfma_f32_16x16x32_bf16(a_h, b_h, acc[t], 0, 0, 0);
            acc[t] = __builtin_amdgcn_mfma_f32_16x16x32_bf16(a_l, b_h, acc[t], 0, 0, 0);
            acc[t] = __builtin_amdgcn_mfma_f32_16x16x32_bf16(a_h, b_l, acc[t], 0, 0, 0);
        }
    }

    // C/D layout: col = lane&15, row = (lane>>4)*4 + reg
    int r0 = m0 + ((lane >> 4) << 2);
    int cc = lane & 15;
#pragma unroll
    for (int t = 0; t < NT; ++t) {
        float bsv = ADD_BIAS ? bias[t * 16 + cc] : 0.f;
#pragma unroll
        for (int r = 0; r < 4; ++r) {
            float val = acc[t][r] + bsv;
            size_t idx = (size_t)(r0 + r) * NC + t * 16 + cc;
            if (HALF_OUT)
                ((__half*)Cv)[idx] = __float2half_rn(val);
            else
                ((float*)Cv)[idx] = val;
        }
    }
}

// ---------------- aggregation: one wave per node, fp16 gather ----------------
// out = relu( sum_e dinv[src]*dinv[node]*h2[src] + dinv^2*h2[node] + bias )
// h2 is fp16; accumulate fp32; write hi/lo bf16 for next GEMM.
__global__ __launch_bounds__(256) void agg_kernel(
    const __half* __restrict__ h2, const int* __restrict__ row_ptr,
    const int* __restrict__ csr_src, const float* __restrict__ dinv,
    const float* __restrict__ bias,
    unsigned short* __restrict__ out_hi, unsigned short* __restrict__ out_lo, int n) {
    int wid = (blockIdx.x * 256 + threadIdx.x) >> 6;
    int lane = threadIdx.x & 63;
    if (wid >= n) return;
    int beg = row_ptr[wid];
    int end = row_ptr[wid + 1];
    float dv = dinv[wid];
    float ax = 0.f, ay = 0.f;
    int loff = lane << 1;
    for (int base = beg; base < end; base += 64) {
        int cnt = end - base;
        if (cnt > 64) cnt = 64;
        int msrc = 0;
        float mw = 0.f;
        if (lane < cnt) {
            msrc = csr_src[base + lane];
            mw = dinv[msrc] * dv;
        }
        int j = 0;
        for (; j + 4 <= cnt; j += 4) {
            int s0 = __shfl(msrc, j), s1 = __shfl(msrc, j + 1);
            int s2 = __shfl(msrc, j + 2), s3 = __shfl(msrc, j + 3);
            float w0 = __shfl(mw, j), w1 = __shfl(mw, j + 1);
            float w2 = __shfl(mw, j + 2), w3 = __shfl(mw, j + 3);
            float2 v0 = __half22float2(*(const __half2*)(h2 + ((size_t)s0 << 7) + loff));
            float2 v1 = __half22float2(*(const __half2*)(h2 + ((size_t)s1 << 7) + loff));
            float2 v2 = __half22float2(*(const __half2*)(h2 + ((size_t)s2 << 7) + loff));
            float2 v3 = __half22float2(*(const __half2*)(h2 + ((size_t)s3 << 7) + loff));
            ax = fmaf(v0.x, w0, ax); ay = fmaf(v0.y, w0, ay);
            ax = fmaf(v1.x, w1, ax); ay = fmaf(v1.y, w1, ay);
            ax = fmaf(v2.x, w2, ax); ay = fmaf(v2.y, w2, ay);
            ax = fmaf(v3.x, w3, ax); ay = fmaf(v3.y, w3, ay);
        }
        for (; j < cnt; ++j) {
            int s = __shfl(msrc, j);
            float w = __shfl(mw, j);
            float2 v = __half22float2(*(const __half2*)(h2 + ((size_t)s << 7) + loff));
            ax = fmaf(v.x, w, ax); ay = fmaf(v.y, w, ay);
        }
    }
    float sn = dv * dv;
    float2 self = __half22float2(*(const __half2*)(h2 + ((size_t)wid << 7) + loff));
    float2 b = *(const float2*)(bias + loff);
    float ox = fmaxf(fmaf(self.x, sn, ax) + b.x, 0.f);
    float oy = fmaxf(fmaf(self.y, sn, ay) + b.y, 0.f);
    unsigned short hx = f2bf_rne(ox), hy = f2bf_rne(oy);
    ushort2 hv, lv;
    hv.x = hx; hv.y = hy;
    lv.x = f2bf_rne(ox - bf2f(hx));
    lv.y = f2bf_rne(oy - bf2f(hy));
    size_t o = ((size_t)wid << 7) + loff;
    *(ushort2*)(out_hi + o) = hv;
    *(ushort2*)(out_lo + o) = lv;
}

extern "C" void kernel_launch(void* const* d_in, const int* in_sizes, int n_in,
                              void* d_out, int out_size, void* d_ws, size_t ws_size,
                              hipStream_t stream) {
    const float* x  = (const float*)d_in[0];
    const int* ei   = (const int*)d_in[1];
    const float* W0 = (const float*)d_in[2];
    const float* b0 = (const float*)d_in[3];
    const float* W1 = (const float*)d_in[4];
    const float* b1 = (const float*)d_in[5];
    const float* W2 = (const float*)d_in[6];
    const float* b2 = (const float*)d_in[7];
    const float* Wl = (const float*)d_in[8];
    const float* bl = (const float*)d_in[9];
    float* out = (float*)d_out;

    const int N = N_NODES;
    const int E = in_sizes[1] / 2;
    const int* row = ei;
    const int* col = ei + E;

    char* ws = (char*)d_ws;
    auto alloc = [&](size_t bytes) {
        char* p = ws;
        ws += (bytes + 255) & ~(size_t)255;
        return p;
    };
    int*   cnt     = (int*)alloc((size_t)N * 4);
    int*   cursor  = (int*)alloc((size_t)N * 4);
    int*   row_ptr = (int*)alloc((size_t)(N + 1) * 4);
    float* dinv    = (float*)alloc((size_t)N * 4);
    int*   csr_src = (int*)alloc((size_t)E * 4);
    __half* h2     = (__half*)alloc((size_t)N * HID * 2);    // GEMM output (fp16)
    unsigned short* h_hi = (unsigned short*)alloc((size_t)N * HID * 2);
    unsigned short* h_lo = (unsigned short*)alloc((size_t)N * HID * 2);
    unsigned short* Wt_hi[4];
    unsigned short* Wt_lo[4];
    for (int i = 0; i < 3; ++i) {
        Wt_hi[i] = (unsigned short*)alloc((size_t)HID * HID * 2);
        Wt_lo[i] = (unsigned short*)alloc((size_t)HID * HID * 2);
    }
    Wt_hi[3] = (unsigned short*)alloc((size_t)CLS * HID * 2);
    Wt_lo[3] = (unsigned short*)alloc((size_t)CLS * HID * 2);
    int* bsum = (int*)alloc((size_t)256 * 4);

    hipMemsetAsync(cnt, 0, (size_t)N * 4, stream);

    int eBlocks = (E + 255) / 256;
    int nBlocks = (N + 255) / 256;
    count_kernel<<<eBlocks, 256, 0, stream>>>(col, cnt, E);
    dinv_kernel<<<nBlocks, 256, 0, stream>>>(cnt, dinv, N);
    block_sum_kernel<<<nBlocks, 256, 0, stream>>>(cnt, bsum, N);
    scan_bsum_kernel<<<1, 256, 0, stream>>>(bsum, nBlocks);
    scan_final_kernel<<<nBlocks, 256, 0, stream>>>(cnt, bsum, row_ptr, cursor, N);
    build_csr_kernel<<<eBlocks, 256, 0, stream>>>(row, col, cursor, csr_src, E);

    // input split + weight transpose-splits (independent of CSR chain)
    int n4 = N * HID / 4;
    split_cast_kernel<<<(n4 + 255) / 256, 256, 0, stream>>>(x, h_hi, h_lo, n4);
    wsplit_kernel<<<(HID * HID + 255) / 256, 256, 0, stream>>>(W0, HID, Wt_hi[0], Wt_lo[0], HID * HID);
    wsplit_kernel<<<(HID * HID + 255) / 256, 256, 0, stream>>>(W1, HID, Wt_hi[1], Wt_lo[1], HID * HID);
    wsplit_kernel<<<(HID * HID + 255) / 256, 256, 0, stream>>>(W2, HID, Wt_hi[2], Wt_lo[2], HID * HID);
    wsplit_kernel<<<(CLS * HID + 255) / 256, 256, 0, stream>>>(Wl, CLS, Wt_hi[3], Wt_lo[3], CLS * HID);

    const int gemmBlocks = (N / 16 + 3) / 4;  // 3125 row-tiles, 4 waves/block
    const int aggBlocks  = (N + 3) / 4;

    // layer 0
    mfma_gemm_split<128, false, true><<<gemmBlocks, 256, 0, stream>>>(h_hi, h_lo, Wt_hi[0], Wt_lo[0], nullptr, h2, N);
    agg_kernel<<<aggBlocks, 256, 0, stream>>>(h2, row_ptr, csr_src, dinv, b0, h_hi, h_lo, N);
    // layer 1
    mfma_gemm_split<128, false, true><<<gemmBlocks, 256, 0, stream>>>(h_hi, h_lo, Wt_hi[1], Wt_lo[1], nullptr, h2, N);
    agg_kernel<<<aggBlocks, 256, 0, stream>>>(h2, row_ptr, csr_src, dinv, b1, h_hi, h_lo, N);
    // layer 2
    mfma_gemm_split<128, false, true><<<gemmBlocks, 256, 0, stream>>>(h_hi, h_lo, Wt_hi[2], Wt_lo[2], nullptr, h2, N);
    agg_kernel<<<aggBlocks, 256, 0, stream>>>(h2, row_ptr, csr_src, dinv, b2, h_hi, h_lo, N);
    // classifier head
    mfma_gemm_split<64, true, false><<<gemmBlocks, 256, 0, stream>>>(h_hi, h_lo, Wt_hi[3], Wt_lo[3], bl, out, N);
}

// Round 5
// 381.319 us; speedup vs baseline: 1.6118x; 1.0530x over previous
//
#include <hip/hip_runtime.h>
#include <hip/hip_bf16.h>
#include <hip/hip_fp16.h>

#define N_NODES 50000
#define HID 128
#define CLS 64

#define NBINS 196        // ceil(50000/256)
#define BIN_CAP 16       // per-bin LDS staging entries
#define BIN_STRIDE 8192  // entries per bin region in global staging (worst-case ~5.5K)
#define LBUF_CAP 6144    // per-bin CSR staging in LDS (worst-case ~3.7K)

typedef __attribute__((ext_vector_type(8))) _Float16 f16x8;
typedef __attribute__((ext_vector_type(4))) float f32x4;

// ---------------- pass 1: bin edges by col>>8 with LDS-staged 64B flushes --------
__global__ __launch_bounds__(256) void bin_kernel(
    const int* __restrict__ row, const int* __restrict__ col,
    int* __restrict__ gcur, unsigned long long* __restrict__ gbuf, int E) {
    __shared__ unsigned long long buf[NBINS][BIN_CAP];
    __shared__ int bcnt[NBINS];
    int tid = threadIdx.x;
    for (int i = tid; i < NBINS; i += 256) bcnt[i] = 0;
    __syncthreads();
    int stride = gridDim.x * 256;
    for (int base = blockIdx.x * 256; base < E; base += stride) {
        int e = base + tid;
        if (e < E) {
            int c = col[e];
            int s = row[e];
            int b = c >> 8;
            unsigned long long entry = ((unsigned long long)(unsigned)c << 32) | (unsigned)s;
            int pos = atomicAdd(&bcnt[b], 1);
            if (pos < BIN_CAP) {
                buf[b][pos] = entry;
            } else {  // rare slow path: direct global append
                int gp = atomicAdd(&gcur[b], 1);
                gbuf[(size_t)b * BIN_STRIDE + gp] = entry;
            }
        }
        __syncthreads();
        if (tid < NBINS) {  // flush full 8-entry (64B) groups
            int cnt = bcnt[tid];
            if (cnt > BIN_CAP) cnt = BIN_CAP;
            int nfull = cnt >> 3;
            if (nfull) {
                int gp = atomicAdd(&gcur[tid], nfull * 8);
                for (int i = 0; i < nfull * 8; ++i)
                    gbuf[(size_t)tid * BIN_STRIDE + gp + i] = buf[tid][i];
                int rem = cnt - nfull * 8;
                for (int i = 0; i < rem; ++i) buf[tid][i] = buf[tid][nfull * 8 + i];
                bcnt[tid] = rem;
            }
        }
        __syncthreads();
    }
    // final flush, sentinel-padded to 64B
    if (tid < NBINS) {
        int cnt = bcnt[tid];
        if (cnt > BIN_CAP) cnt = BIN_CAP;
        if (cnt > 0) {
            int padded = (cnt + 7) & ~7;
            for (int i = cnt; i < padded; ++i) buf[tid][i] = ~0ull;
            int gp = atomicAdd(&gcur[tid], padded);
            for (int i = 0; i < padded; ++i)
                gbuf[(size_t)tid * BIN_STRIDE + gp + i] = buf[tid][i];
        }
    }
}

// ---------------- pass 2a: per-node degree from binned edges ----------------
__global__ __launch_bounds__(256) void bin_count_kernel(
    const int* __restrict__ gcur, const unsigned long long* __restrict__ gbuf,
    int* __restrict__ cnt, int n) {
    __shared__ int lcnt[256];
    lcnt[threadIdx.x] = 0;
    __syncthreads();
    int b = blockIdx.x;
    int nE = gcur[b];
    const unsigned long long* src = gbuf + (size_t)b * BIN_STRIDE;
    for (int i = threadIdx.x; i < nE; i += 256) {
        unsigned c = (unsigned)(src[i] >> 32);
        if (c != 0xFFFFFFFFu) atomicAdd(&lcnt[c & 255], 1);
    }
    __syncthreads();
    int node = b * 256 + threadIdx.x;
    if (node < n) cnt[node] = lcnt[threadIdx.x];
}

// ---------------- multi-block exclusive scan ----------------
__global__ __launch_bounds__(256) void block_sum_kernel(const int* __restrict__ cnt,
                                                        int* __restrict__ bsum, int n) {
    int i = blockIdx.x * 256 + threadIdx.x;
    int v = (i < n) ? cnt[i] : 0;
#pragma unroll
    for (int off = 32; off; off >>= 1) v += __shfl_down(v, off, 64);
    __shared__ int ws[4];
    if ((threadIdx.x & 63) == 0) ws[threadIdx.x >> 6] = v;
    __syncthreads();
    if (threadIdx.x == 0) bsum[blockIdx.x] = ws[0] + ws[1] + ws[2] + ws[3];
}

__global__ __launch_bounds__(256) void scan_bsum_kernel(int* __restrict__ bsum, int nb) {
    __shared__ int s[256];
    int t = threadIdx.x;
    int v = (t < nb) ? bsum[t] : 0;
    s[t] = v;
    __syncthreads();
#pragma unroll
    for (int off = 1; off < 256; off <<= 1) {
        int u = (t >= off) ? s[t - off] : 0;
        __syncthreads();
        s[t] += u;
        __syncthreads();
    }
    if (t < nb) bsum[t] = s[t] - v;  // exclusive
}

// row_ptr + dinv fused
__global__ __launch_bounds__(256) void scan_final_kernel(const int* __restrict__ cnt,
                                                         const int* __restrict__ bsum_excl,
                                                         int* __restrict__ row_ptr,
                                                         float* __restrict__ dinv, int n) {
    __shared__ int s[256];
    int t = threadIdx.x;
    int i = blockIdx.x * 256 + t;
    int v = (i < n) ? cnt[i] : 0;
    s[t] = v;
    __syncthreads();
#pragma unroll
    for (int off = 1; off < 256; off <<= 1) {
        int u = (t >= off) ? s[t - off] : 0;
        __syncthreads();
        s[t] += u;
        __syncthreads();
    }
    int excl = bsum_excl[blockIdx.x] + s[t] - v;
    if (i < n) {
        row_ptr[i] = excl;
        dinv[i] = rsqrtf((float)v + 1.0f);
        if (i == n - 1) row_ptr[n] = excl + v;
    }
}

// ---------------- pass 2b: build CSR segment per bin in LDS, coalesced write ------
__global__ __launch_bounds__(256) void csr_scatter_kernel(
    const int* __restrict__ gcur, const unsigned long long* __restrict__ gbuf,
    const int* __restrict__ row_ptr, int* __restrict__ csr_src, int n) {
    __shared__ int lcnt[256];
    __shared__ int lcur[256];
    __shared__ int ss[256];
    __shared__ int lbuf[LBUF_CAP];
    int tid = threadIdx.x;
    lcnt[tid] = 0;
    __syncthreads();
    int b = blockIdx.x;
    int nE = gcur[b];
    const unsigned long long* src = gbuf + (size_t)b * BIN_STRIDE;
    for (int i = tid; i < nE; i += 256) {
        unsigned c = (unsigned)(src[i] >> 32);
        if (c != 0xFFFFFFFFu) atomicAdd(&lcnt[c & 255], 1);
    }
    __syncthreads();
    int v = lcnt[tid];
    ss[tid] = v;
    __syncthreads();
#pragma unroll
    for (int off = 1; off < 256; off <<= 1) {
        int u = (tid >= off) ? ss[tid - off] : 0;
        __syncthreads();
        ss[tid] += u;
        __syncthreads();
    }
    lcur[tid] = ss[tid] - v;  // exclusive local offset
    int total = ss[255];
    __syncthreads();
    for (int i = tid; i < nE; i += 256) {
        unsigned long long e = src[i];
        unsigned c = (unsigned)(e >> 32);
        if (c != 0xFFFFFFFFu) {
            int pos = atomicAdd(&lcur[c & 255], 1);
            lbuf[pos] = (int)(unsigned)(e & 0xFFFFFFFFu);
        }
    }
    __syncthreads();
    int base = row_ptr[b * 256];
    for (int i = tid; i < total; i += 256) csr_src[base + i] = lbuf[i];
}

// ---------------- x fp32 -> fp16, vectorized x4 ----------------
__global__ __launch_bounds__(256) void cast_x_kernel(const float* __restrict__ in,
                                                     __half* __restrict__ out, int n4) {
    int i = blockIdx.x * 256 + threadIdx.x;
    if (i >= n4) return;
    float4 v = ((const float4*)in)[i];
    __half2 a = __float22half2_rn(make_float2(v.x, v.y));
    __half2 c = __float22half2_rn(make_float2(v.z, v.w));
    ((__half2*)out)[i * 2] = a;
    ((__half2*)out)[i * 2 + 1] = c;
}

// ---------------- all W [K=128, NCdim] fp32 -> transposed [n][k] f16 hi/lo --------
__global__ __launch_bounds__(256) void wsplit_all_kernel(
    const float* __restrict__ W0, const float* __restrict__ W1,
    const float* __restrict__ W2, const float* __restrict__ Wl,
    __half* __restrict__ o0h, __half* __restrict__ o0l,
    __half* __restrict__ o1h, __half* __restrict__ o1l,
    __half* __restrict__ o2h, __half* __restrict__ o2l,
    __half* __restrict__ o3h, __half* __restrict__ o3l) {
    int idx = blockIdx.x * 256 + threadIdx.x;
    const float* W;
    __half *oh, *ol;
    int NCdim, local;
    if (idx < 16384)      { W = W0; oh = o0h; ol = o0l; NCdim = 128; local = idx; }
    else if (idx < 32768) { W = W1; oh = o1h; ol = o1l; NCdim = 128; local = idx - 16384; }
    else if (idx < 49152) { W = W2; oh = o2h; ol = o2l; NCdim = 128; local = idx - 32768; }
    else if (idx < 57344) { W = Wl; oh = o3h; ol = o3l; NCdim = 64;  local = idx - 49152; }
    else return;
    int nn = local >> 7;
    int k = local & 127;
    float v = W[(size_t)k * NCdim + nn];
    __half h = __float2half_rn(v);
    oh[local] = h;
    ol[local] = __float2half_rn(v - __half2float(h));
}

// ---------------- f16 MFMA GEMM: C = A @ (Wh+Wl) (+bias), K=128 ----------------
// A fp16 [M,128] k-contig; W f16 hi/lo [NC,128] n-major k-contig. No LDS.
template<int NC, bool ADD_BIAS, bool HALF_OUT>
__global__ __launch_bounds__(256) void mfma_gemm_f16(
    const __half* __restrict__ A, const __half* __restrict__ Bh,
    const __half* __restrict__ Bl, const float* __restrict__ bias,
    void* __restrict__ Cv, int M) {
    constexpr int NT = NC / 16;
    int lane = threadIdx.x & 63;
    int rowTile = blockIdx.x * 4 + (threadIdx.x >> 6);
    int m0 = rowTile << 4;
    if (m0 >= M) return;
    int mr = lane & 15;
    int kq = (lane >> 4) << 3;  // 0,8,16,24

    const __half* ap = A + (size_t)(m0 + mr) * 128 + kq;
    const __half* bh = Bh + (size_t)mr * 128 + kq;
    const __half* bl = Bl + (size_t)mr * 128 + kq;

    f32x4 acc[NT];
#pragma unroll
    for (int t = 0; t < NT; ++t) acc[t] = (f32x4){0.f, 0.f, 0.f, 0.f};

#pragma unroll
    for (int kc = 0; kc < 128; kc += 32) {
        f16x8 a = *(const f16x8*)(ap + kc);
#pragma unroll
        for (int t = 0; t < NT; ++t) {
            f16x8 wh = *(const f16x8*)(bh + (size_t)t * 16 * 128 + kc);
            f16x8 wl = *(const f16x8*)(bl + (size_t)t * 16 * 128 + kc);
            acc[t] = __builtin_amdgcn_mfma_f32_16x16x32_f16(a, wh, acc[t], 0, 0, 0);
            acc[t] = __builtin_amdgcn_mfma_f32_16x16x32_f16(a, wl, acc[t], 0, 0, 0);
        }
    }

    // C/D layout: col = lane&15, row = (lane>>4)*4 + reg
    int r0 = m0 + ((lane >> 4) << 2);
    int cc = lane & 15;
#pragma unroll
    for (int t = 0; t < NT; ++t) {
        float bsv = ADD_BIAS ? bias[t * 16 + cc] : 0.f;
#pragma unroll
        for (int r = 0; r < 4; ++r) {
            float val = acc[t][r] + bsv;
            size_t idx = (size_t)(r0 + r) * NC + t * 16 + cc;
            if (HALF_OUT)
                ((__half*)Cv)[idx] = __float2half_rn(val);
            else
                ((float*)Cv)[idx] = val;
        }
    }
}

// ---------------- aggregation: one wave per node, fp16 gather, fp16 out -----------
__global__ __launch_bounds__(256) void agg_kernel(
    const __half* __restrict__ h2, const int* __restrict__ row_ptr,
    const int* __restrict__ csr_src, const float* __restrict__ dinv,
    const float* __restrict__ bias, __half* __restrict__ outA, int n) {
    int wid = (blockIdx.x * 256 + threadIdx.x) >> 6;
    int lane = threadIdx.x & 63;
    if (wid >= n) return;
    int beg = row_ptr[wid];
    int end = row_ptr[wid + 1];
    float dv = dinv[wid];
    float ax = 0.f, ay = 0.f;
    int loff = lane << 1;
    for (int base = beg; base < end; base += 64) {
        int cnt = end - base;
        if (cnt > 64) cnt = 64;
        int msrc = 0;
        float mw = 0.f;
        if (lane < cnt) {
            msrc = csr_src[base + lane];
            mw = dinv[msrc] * dv;
        }
        int j = 0;
        for (; j + 8 <= cnt; j += 8) {
            int s0 = __shfl(msrc, j),     s1 = __shfl(msrc, j + 1);
            int s2 = __shfl(msrc, j + 2), s3 = __shfl(msrc, j + 3);
            int s4 = __shfl(msrc, j + 4), s5 = __shfl(msrc, j + 5);
            int s6 = __shfl(msrc, j + 6), s7 = __shfl(msrc, j + 7);
            float w0 = __shfl(mw, j),     w1 = __shfl(mw, j + 1);
            float w2 = __shfl(mw, j + 2), w3 = __shfl(mw, j + 3);
            float w4 = __shfl(mw, j + 4), w5 = __shfl(mw, j + 5);
            float w6 = __shfl(mw, j + 6), w7 = __shfl(mw, j + 7);
            float2 v0 = __half22float2(*(const __half2*)(h2 + ((size_t)s0 << 7) + loff));
            float2 v1 = __half22float2(*(const __half2*)(h2 + ((size_t)s1 << 7) + loff));
            float2 v2 = __half22float2(*(const __half2*)(h2 + ((size_t)s2 << 7) + loff));
            float2 v3 = __half22float2(*(const __half2*)(h2 + ((size_t)s3 << 7) + loff));
            float2 v4 = __half22float2(*(const __half2*)(h2 + ((size_t)s4 << 7) + loff));
            float2 v5 = __half22float2(*(const __half2*)(h2 + ((size_t)s5 << 7) + loff));
            float2 v6 = __half22float2(*(const __half2*)(h2 + ((size_t)s6 << 7) + loff));
            float2 v7 = __half22float2(*(const __half2*)(h2 + ((size_t)s7 << 7) + loff));
            ax = fmaf(v0.x, w0, ax); ay = fmaf(v0.y, w0, ay);
            ax = fmaf(v1.x, w1, ax); ay = fmaf(v1.y, w1, ay);
            ax = fmaf(v2.x, w2, ax); ay = fmaf(v2.y, w2, ay);
            ax = fmaf(v3.x, w3, ax); ay = fmaf(v3.y, w3, ay);
            ax = fmaf(v4.x, w4, ax); ay = fmaf(v4.y, w4, ay);
            ax = fmaf(v5.x, w5, ax); ay = fmaf(v5.y, w5, ay);
            ax = fmaf(v6.x, w6, ax); ay = fmaf(v6.y, w6, ay);
            ax = fmaf(v7.x, w7, ax); ay = fmaf(v7.y, w7, ay);
        }
        for (; j < cnt; ++j) {
            int s = __shfl(msrc, j);
            float w = __shfl(mw, j);
            float2 v = __half22float2(*(const __half2*)(h2 + ((size_t)s << 7) + loff));
            ax = fmaf(v.x, w, ax); ay = fmaf(v.y, w, ay);
        }
    }
    float sn = dv * dv;
    float2 self = __half22float2(*(const __half2*)(h2 + ((size_t)wid << 7) + loff));
    float2 b = *(const float2*)(bias + loff);
    float ox = fmaxf(fmaf(self.x, sn, ax) + b.x, 0.f);
    float oy = fmaxf(fmaf(self.y, sn, ay) + b.y, 0.f);
    *(__half2*)(outA + ((size_t)wid << 7) + loff) = __float22half2_rn(make_float2(ox, oy));
}

extern "C" void kernel_launch(void* const* d_in, const int* in_sizes, int n_in,
                              void* d_out, int out_size, void* d_ws, size_t ws_size,
                              hipStream_t stream) {
    const float* x  = (const float*)d_in[0];
    const int* ei   = (const int*)d_in[1];
    const float* W0 = (const float*)d_in[2];
    const float* b0 = (const float*)d_in[3];
    const float* W1 = (const float*)d_in[4];
    const float* b1 = (const float*)d_in[5];
    const float* W2 = (const float*)d_in[6];
    const float* b2 = (const float*)d_in[7];
    const float* Wl = (const float*)d_in[8];
    const float* bl = (const float*)d_in[9];
    float* out = (float*)d_out;

    const int N = N_NODES;
    const int E = in_sizes[1] / 2;
    const int* row = ei;
    const int* col = ei + E;

    char* ws = (char*)d_ws;
    auto alloc = [&](size_t bytes) {
        char* p = ws;
        ws += (bytes + 255) & ~(size_t)255;
        return p;
    };
    int*   gcur    = (int*)alloc((size_t)NBINS * 4);
    unsigned long long* gbuf = (unsigned long long*)alloc((size_t)NBINS * BIN_STRIDE * 8);
    int*   cnt     = (int*)alloc((size_t)N * 4);
    int*   row_ptr = (int*)alloc((size_t)(N + 1) * 4);
    float* dinv    = (float*)alloc((size_t)N * 4);
    int*   csr_src = (int*)alloc((size_t)E * 4);
    int*   bsum    = (int*)alloc((size_t)256 * 4);
    __half* h2     = (__half*)alloc((size_t)N * HID * 2);  // GEMM out (gather source)
    __half* hA     = (__half*)alloc((size_t)N * HID * 2);  // agg out (next GEMM A)
    __half* Wt_h[4];
    __half* Wt_l[4];
    for (int i = 0; i < 3; ++i) {
        Wt_h[i] = (__half*)alloc((size_t)HID * HID * 2);
        Wt_l[i] = (__half*)alloc((size_t)HID * HID * 2);
    }
    Wt_h[3] = (__half*)alloc((size_t)CLS * HID * 2);
    Wt_l[3] = (__half*)alloc((size_t)CLS * HID * 2);

    hipMemsetAsync(gcur, 0, (size_t)NBINS * 4, stream);

    // CSR pipeline
    bin_kernel<<<256, 256, 0, stream>>>(row, col, gcur, gbuf, E);
    bin_count_kernel<<<NBINS, 256, 0, stream>>>(gcur, gbuf, cnt, N);
    int nBlocks = (N + 255) / 256;  // = 196
    block_sum_kernel<<<nBlocks, 256, 0, stream>>>(cnt, bsum, N);
    scan_bsum_kernel<<<1, 256, 0, stream>>>(bsum, nBlocks);
    scan_final_kernel<<<nBlocks, 256, 0, stream>>>(cnt, bsum, row_ptr, dinv, N);
    csr_scatter_kernel<<<NBINS, 256, 0, stream>>>(gcur, gbuf, row_ptr, csr_src, N);

    // input cast + weight splits (independent of CSR chain)
    int n4 = N * HID / 4;
    cast_x_kernel<<<(n4 + 255) / 256, 256, 0, stream>>>(x, hA, n4);
    wsplit_all_kernel<<<224, 256, 0, stream>>>(W0, W1, W2, Wl,
        Wt_h[0], Wt_l[0], Wt_h[1], Wt_l[1], Wt_h[2], Wt_l[2], Wt_h[3], Wt_l[3]);

    const int gemmBlocks = (N / 16 + 3) / 4;  // 782 blocks x 4 waves >= 3125 tiles
    const int aggBlocks  = (N + 3) / 4;

    // layer 0
    mfma_gemm_f16<128, false, true><<<gemmBlocks, 256, 0, stream>>>(hA, Wt_h[0], Wt_l[0], nullptr, h2, N);
    agg_kernel<<<aggBlocks, 256, 0, stream>>>(h2, row_ptr, csr_src, dinv, b0, hA, N);
    // layer 1
    mfma_gemm_f16<128, false, true><<<gemmBlocks, 256, 0, stream>>>(hA, Wt_h[1], Wt_l[1], nullptr, h2, N);
    agg_kernel<<<aggBlocks, 256, 0, stream>>>(h2, row_ptr, csr_src, dinv, b1, hA, N);
    // layer 2
    mfma_gemm_f16<128, false, true><<<gemmBlocks, 256, 0, stream>>>(hA, Wt_h[2], Wt_l[2], nullptr, h2, N);
    agg_kernel<<<aggBlocks, 256, 0, stream>>>(h2, row_ptr, csr_src, dinv, b2, hA, N);
    // classifier head
    mfma_gemm_f16<64, true, false><<<gemmBlocks, 256, 0, stream>>>(hA, Wt_h[3], Wt_l[3], bl, out, N);
}

// Round 6
// 350.743 us; speedup vs baseline: 1.7523x; 1.0872x over previous
//
#include <hip/hip_runtime.h>
#include <hip/hip_bf16.h>
#include <hip/hip_fp16.h>

#define N_NODES 50000
#define HID 128
#define CLS 64

#define NBINS 196        // ceil(50000/256)
#define NBLK 256         // scatter/hist blocks
#define LBUF_CAP 6144    // per-bin CSR staging in LDS (bin degree ~3277 +/- 57)

typedef __attribute__((ext_vector_type(8))) _Float16 f16x8;
typedef __attribute__((ext_vector_type(4))) float f32x4;

// ---------------- pass 1a: per-(block,bin) histogram ----------------
__global__ __launch_bounds__(256) void hist_kernel(const int* __restrict__ col,
                                                   int* __restrict__ hist, int E, int chunk) {
    __shared__ int h[NBINS];
    for (int i = threadIdx.x; i < NBINS; i += 256) h[i] = 0;
    __syncthreads();
    int b = blockIdx.x;
    int beg = b * chunk;
    int end = min(E, beg + chunk);
    for (int i = beg + threadIdx.x; i < end; i += 256)
        atomicAdd(&h[col[i] >> 8], 1);
    __syncthreads();
    for (int i = threadIdx.x; i < NBINS; i += 256)
        hist[i * NBLK + b] = h[i];  // bin-major, block-minor
}

// ---------------- generic 3-phase exclusive scan pieces ----------------
__global__ __launch_bounds__(256) void block_sum_kernel(const int* __restrict__ cnt,
                                                        int* __restrict__ bsum, int n) {
    int i = blockIdx.x * 256 + threadIdx.x;
    int v = (i < n) ? cnt[i] : 0;
#pragma unroll
    for (int off = 32; off; off >>= 1) v += __shfl_down(v, off, 64);
    __shared__ int ws[4];
    if ((threadIdx.x & 63) == 0) ws[threadIdx.x >> 6] = v;
    __syncthreads();
    if (threadIdx.x == 0) bsum[blockIdx.x] = ws[0] + ws[1] + ws[2] + ws[3];
}

__global__ __launch_bounds__(256) void scan_bsum_kernel(int* __restrict__ bsum, int nb) {
    __shared__ int s[256];
    int t = threadIdx.x;
    int v = (t < nb) ? bsum[t] : 0;
    s[t] = v;
    __syncthreads();
#pragma unroll
    for (int off = 1; off < 256; off <<= 1) {
        int u = (t >= off) ? s[t - off] : 0;
        __syncthreads();
        s[t] += u;
        __syncthreads();
    }
    if (t < nb) bsum[t] = s[t] - v;  // exclusive
}

// plain variant: exclusive scan -> outv[0..n], outv[n] = total
__global__ __launch_bounds__(256) void scan_final_plain(const int* __restrict__ cnt,
                                                        const int* __restrict__ bsum_excl,
                                                        int* __restrict__ outv, int n) {
    __shared__ int s[256];
    int t = threadIdx.x;
    int i = blockIdx.x * 256 + t;
    int v = (i < n) ? cnt[i] : 0;
    s[t] = v;
    __syncthreads();
#pragma unroll
    for (int off = 1; off < 256; off <<= 1) {
        int u = (t >= off) ? s[t - off] : 0;
        __syncthreads();
        s[t] += u;
        __syncthreads();
    }
    int excl = bsum_excl[blockIdx.x] + s[t] - v;
    if (i < n) {
        outv[i] = excl;
        if (i == n - 1) outv[n] = excl + v;
    }
}

// node variant: row_ptr + dinv fused
__global__ __launch_bounds__(256) void scan_final_kernel(const int* __restrict__ cnt,
                                                         const int* __restrict__ bsum_excl,
                                                         int* __restrict__ row_ptr,
                                                         float* __restrict__ dinv, int n) {
    __shared__ int s[256];
    int t = threadIdx.x;
    int i = blockIdx.x * 256 + t;
    int v = (i < n) ? cnt[i] : 0;
    s[t] = v;
    __syncthreads();
#pragma unroll
    for (int off = 1; off < 256; off <<= 1) {
        int u = (t >= off) ? s[t - off] : 0;
        __syncthreads();
        s[t] += u;
        __syncthreads();
    }
    int excl = bsum_excl[blockIdx.x] + s[t] - v;
    if (i < n) {
        row_ptr[i] = excl;
        dinv[i] = rsqrtf((float)v + 1.0f);
        if (i == n - 1) row_ptr[n] = excl + v;
    }
}

// ---------------- pass 1b: scatter edges to bin-sorted compact gbuf ----------------
__global__ __launch_bounds__(256) void scatter_kernel(
    const int* __restrict__ row, const int* __restrict__ col,
    const int* __restrict__ hofs, unsigned long long* __restrict__ gbuf,
    int E, int chunk) {
    __shared__ int cur[NBINS];
    int b = blockIdx.x;
    for (int i = threadIdx.x; i < NBINS; i += 256) cur[i] = hofs[i * NBLK + b];
    __syncthreads();
    int beg = b * chunk;
    int end = min(E, beg + chunk);
    for (int i = beg + threadIdx.x; i < end; i += 256) {
        int c = col[i], s = row[i];
        int pos = atomicAdd(&cur[c >> 8], 1);
        gbuf[pos] = ((unsigned long long)(unsigned)c << 32) | (unsigned)s;
    }
}

// ---------------- pass 2a: per-node degree from bin-sorted edges ----------------
__global__ __launch_bounds__(256) void bin_count_kernel(
    const int* __restrict__ hofs, const unsigned long long* __restrict__ gbuf,
    int* __restrict__ cnt, int n, int E) {
    __shared__ int lcnt[256];
    lcnt[threadIdx.x] = 0;
    __syncthreads();
    int b = blockIdx.x;
    int beg = hofs[b * NBLK];
    int end = (b == NBINS - 1) ? E : hofs[(b + 1) * NBLK];
    for (int i = beg + threadIdx.x; i < end; i += 256)
        atomicAdd(&lcnt[(int)((gbuf[i] >> 32) & 255u)], 1);
    __syncthreads();
    int node = b * 256 + threadIdx.x;
    if (node < n) cnt[node] = lcnt[threadIdx.x];
}

// ---------------- pass 2b: build CSR segment per bin in LDS, coalesced write ------
__global__ __launch_bounds__(256) void csr_scatter_kernel(
    const int* __restrict__ hofs, const unsigned long long* __restrict__ gbuf,
    const int* __restrict__ row_ptr, int* __restrict__ csr_src, int n, int E) {
    __shared__ int lcnt[256];
    __shared__ int lcur[256];
    __shared__ int ss[256];
    __shared__ int lbuf[LBUF_CAP];
    int tid = threadIdx.x;
    lcnt[tid] = 0;
    __syncthreads();
    int b = blockIdx.x;
    int beg = hofs[b * NBLK];
    int end = (b == NBINS - 1) ? E : hofs[(b + 1) * NBLK];
    for (int i = beg + tid; i < end; i += 256)
        atomicAdd(&lcnt[(int)((gbuf[i] >> 32) & 255u)], 1);
    __syncthreads();
    int v = lcnt[tid];
    ss[tid] = v;
    __syncthreads();
#pragma unroll
    for (int off = 1; off < 256; off <<= 1) {
        int u = (tid >= off) ? ss[tid - off] : 0;
        __syncthreads();
        ss[tid] += u;
        __syncthreads();
    }
    lcur[tid] = ss[tid] - v;  // exclusive local offset
    int total = ss[255];
    __syncthreads();
    for (int i = beg + tid; i < end; i += 256) {
        unsigned long long e = gbuf[i];
        int pos = atomicAdd(&lcur[(int)((e >> 32) & 255u)], 1);
        lbuf[pos] = (int)(unsigned)(e & 0xFFFFFFFFu);
    }
    __syncthreads();
    int base = row_ptr[b * 256];
    for (int i = tid; i < total; i += 256) csr_src[base + i] = lbuf[i];
}

// ---------------- x fp32 -> fp16, vectorized x4 ----------------
__global__ __launch_bounds__(256) void cast_x_kernel(const float* __restrict__ in,
                                                     __half* __restrict__ out, int n4) {
    int i = blockIdx.x * 256 + threadIdx.x;
    if (i >= n4) return;
    float4 v = ((const float4*)in)[i];
    __half2 a = __float22half2_rn(make_float2(v.x, v.y));
    __half2 c = __float22half2_rn(make_float2(v.z, v.w));
    ((__half2*)out)[i * 2] = a;
    ((__half2*)out)[i * 2 + 1] = c;
}

// ---------------- all W [K=128, NCdim] fp32 -> transposed [n][k] f16 hi/lo --------
__global__ __launch_bounds__(256) void wsplit_all_kernel(
    const float* __restrict__ W0, const float* __restrict__ W1,
    const float* __restrict__ W2, const float* __restrict__ Wl,
    __half* __restrict__ o0h, __half* __restrict__ o0l,
    __half* __restrict__ o1h, __half* __restrict__ o1l,
    __half* __restrict__ o2h, __half* __restrict__ o2l,
    __half* __restrict__ o3h, __half* __restrict__ o3l) {
    int idx = blockIdx.x * 256 + threadIdx.x;
    const float* W;
    __half *oh, *ol;
    int NCdim, local;
    if (idx < 16384)      { W = W0; oh = o0h; ol = o0l; NCdim = 128; local = idx; }
    else if (idx < 32768) { W = W1; oh = o1h; ol = o1l; NCdim = 128; local = idx - 16384; }
    else if (idx < 49152) { W = W2; oh = o2h; ol = o2l; NCdim = 128; local = idx - 32768; }
    else if (idx < 57344) { W = Wl; oh = o3h; ol = o3l; NCdim = 64;  local = idx - 49152; }
    else return;
    int nn = local >> 7;
    int k = local & 127;
    float v = W[(size_t)k * NCdim + nn];
    __half h = __float2half_rn(v);
    oh[local] = h;
    ol[local] = __float2half_rn(v - __half2float(h));
}

// ---------------- f16 MFMA GEMM: C = A @ (Wh+Wl) (+bias), K=128 ----------------
template<int NC, bool ADD_BIAS, bool HALF_OUT>
__global__ __launch_bounds__(256) void mfma_gemm_f16(
    const __half* __restrict__ A, const __half* __restrict__ Bh,
    const __half* __restrict__ Bl, const float* __restrict__ bias,
    void* __restrict__ Cv, int M) {
    constexpr int NT = NC / 16;
    int lane = threadIdx.x & 63;
    int rowTile = blockIdx.x * 4 + (threadIdx.x >> 6);
    int m0 = rowTile << 4;
    if (m0 >= M) return;
    int mr = lane & 15;
    int kq = (lane >> 4) << 3;  // 0,8,16,24

    const __half* ap = A + (size_t)(m0 + mr) * 128 + kq;
    const __half* bh = Bh + (size_t)mr * 128 + kq;
    const __half* bl = Bl + (size_t)mr * 128 + kq;

    f32x4 acc[NT];
#pragma unroll
    for (int t = 0; t < NT; ++t) acc[t] = (f32x4){0.f, 0.f, 0.f, 0.f};

#pragma unroll
    for (int kc = 0; kc < 128; kc += 32) {
        f16x8 a = *(const f16x8*)(ap + kc);
#pragma unroll
        for (int t = 0; t < NT; ++t) {
            f16x8 wh = *(const f16x8*)(bh + (size_t)t * 16 * 128 + kc);
            f16x8 wl = *(const f16x8*)(bl + (size_t)t * 16 * 128 + kc);
            acc[t] = __builtin_amdgcn_mfma_f32_16x16x32_f16(a, wh, acc[t], 0, 0, 0);
            acc[t] = __builtin_amdgcn_mfma_f32_16x16x32_f16(a, wl, acc[t], 0, 0, 0);
        }
    }

    // C/D layout: col = lane&15, row = (lane>>4)*4 + reg
    int r0 = m0 + ((lane >> 4) << 2);
    int cc = lane & 15;
#pragma unroll
    for (int t = 0; t < NT; ++t) {
        float bsv = ADD_BIAS ? bias[t * 16 + cc] : 0.f;
#pragma unroll
        for (int r = 0; r < 4; ++r) {
            float val = acc[t][r] + bsv;
            size_t idx = (size_t)(r0 + r) * NC + t * 16 + cc;
            if (HALF_OUT)
                ((__half*)Cv)[idx] = __float2half_rn(val);
            else
                ((float*)Cv)[idx] = val;
        }
    }
}

// ---------------- aggregation: one wave per node, fp16 gather, fp16 out -----------
__global__ __launch_bounds__(256) void agg_kernel(
    const __half* __restrict__ h2, const int* __restrict__ row_ptr,
    const int* __restrict__ csr_src, const float* __restrict__ dinv,
    const float* __restrict__ bias, __half* __restrict__ outA, int n) {
    int wid = (blockIdx.x * 256 + threadIdx.x) >> 6;
    int lane = threadIdx.x & 63;
    if (wid >= n) return;
    int beg = row_ptr[wid];
    int end = row_ptr[wid + 1];
    float dv = dinv[wid];
    float ax = 0.f, ay = 0.f;
    int loff = lane << 1;
    for (int base = beg; base < end; base += 64) {
        int cnt = end - base;
        if (cnt > 64) cnt = 64;
        int msrc = 0;
        float mw = 0.f;
        if (lane < cnt) {
            msrc = csr_src[base + lane];
            mw = dinv[msrc] * dv;
        }
        int j = 0;
        for (; j + 8 <= cnt; j += 8) {
            int s0 = __shfl(msrc, j),     s1 = __shfl(msrc, j + 1);
            int s2 = __shfl(msrc, j + 2), s3 = __shfl(msrc, j + 3);
            int s4 = __shfl(msrc, j + 4), s5 = __shfl(msrc, j + 5);
            int s6 = __shfl(msrc, j + 6), s7 = __shfl(msrc, j + 7);
            float w0 = __shfl(mw, j),     w1 = __shfl(mw, j + 1);
            float w2 = __shfl(mw, j + 2), w3 = __shfl(mw, j + 3);
            float w4 = __shfl(mw, j + 4), w5 = __shfl(mw, j + 5);
            float w6 = __shfl(mw, j + 6), w7 = __shfl(mw, j + 7);
            float2 v0 = __half22float2(*(const __half2*)(h2 + ((size_t)s0 << 7) + loff));
            float2 v1 = __half22float2(*(const __half2*)(h2 + ((size_t)s1 << 7) + loff));
            float2 v2 = __half22float2(*(const __half2*)(h2 + ((size_t)s2 << 7) + loff));
            float2 v3 = __half22float2(*(const __half2*)(h2 + ((size_t)s3 << 7) + loff));
            float2 v4 = __half22float2(*(const __half2*)(h2 + ((size_t)s4 << 7) + loff));
            float2 v5 = __half22float2(*(const __half2*)(h2 + ((size_t)s5 << 7) + loff));
            float2 v6 = __half22float2(*(const __half2*)(h2 + ((size_t)s6 << 7) + loff));
            float2 v7 = __half22float2(*(const __half2*)(h2 + ((size_t)s7 << 7) + loff));
            ax = fmaf(v0.x, w0, ax); ay = fmaf(v0.y, w0, ay);
            ax = fmaf(v1.x, w1, ax); ay = fmaf(v1.y, w1, ay);
            ax = fmaf(v2.x, w2, ax); ay = fmaf(v2.y, w2, ay);
            ax = fmaf(v3.x, w3, ax); ay = fmaf(v3.y, w3, ay);
            ax = fmaf(v4.x, w4, ax); ay = fmaf(v4.y, w4, ay);
            ax = fmaf(v5.x, w5, ax); ay = fmaf(v5.y, w5, ay);
            ax = fmaf(v6.x, w6, ax); ay = fmaf(v6.y, w6, ay);
            ax = fmaf(v7.x, w7, ax); ay = fmaf(v7.y, w7, ay);
        }
        for (; j < cnt; ++j) {
            int s = __shfl(msrc, j);
            float w = __shfl(mw, j);
            float2 v = __half22float2(*(const __half2*)(h2 + ((size_t)s << 7) + loff));
            ax = fmaf(v.x, w, ax); ay = fmaf(v.y, w, ay);
        }
    }
    float sn = dv * dv;
    float2 self = __half22float2(*(const __half2*)(h2 + ((size_t)wid << 7) + loff));
    float2 b = *(const float2*)(bias + loff);
    float ox = fmaxf(fmaf(self.x, sn, ax) + b.x, 0.f);
    float oy = fmaxf(fmaf(self.y, sn, ay) + b.y, 0.f);
    *(__half2*)(outA + ((size_t)wid << 7) + loff) = __float22half2_rn(make_float2(ox, oy));
}

extern "C" void kernel_launch(void* const* d_in, const int* in_sizes, int n_in,
                              void* d_out, int out_size, void* d_ws, size_t ws_size,
                              hipStream_t stream) {
    const float* x  = (const float*)d_in[0];
    const int* ei   = (const int*)d_in[1];
    const float* W0 = (const float*)d_in[2];
    const float* b0 = (const float*)d_in[3];
    const float* W1 = (const float*)d_in[4];
    const float* b1 = (const float*)d_in[5];
    const float* W2 = (const float*)d_in[6];
    const float* b2 = (const float*)d_in[7];
    const float* Wl = (const float*)d_in[8];
    const float* bl = (const float*)d_in[9];
    float* out = (float*)d_out;

    const int N = N_NODES;
    const int E = in_sizes[1] / 2;
    const int* row = ei;
    const int* col = ei + E;
    const int chunk = (E + NBLK - 1) / NBLK;
    const int HTOT = NBINS * NBLK;  // 50176

    char* ws = (char*)d_ws;
    auto alloc = [&](size_t bytes) {
        char* p = ws;
        ws += (bytes + 255) & ~(size_t)255;
        return p;
    };
    int*   hist    = (int*)alloc((size_t)HTOT * 4);
    int*   hofs    = (int*)alloc((size_t)(HTOT + 1) * 4);
    unsigned long long* gbuf = (unsigned long long*)alloc((size_t)E * 8);
    int*   cnt     = (int*)alloc((size_t)N * 4);
    int*   row_ptr = (int*)alloc((size_t)(N + 1) * 4);
    float* dinv    = (float*)alloc((size_t)N * 4);
    int*   csr_src = (int*)alloc((size_t)E * 4);
    int*   bsum1   = (int*)alloc((size_t)256 * 4);
    int*   bsum2   = (int*)alloc((size_t)256 * 4);
    __half* h2     = (__half*)alloc((size_t)N * HID * 2);  // GEMM out (gather source)
    __half* hA     = (__half*)alloc((size_t)N * HID * 2);  // agg out (next GEMM A)
    __half* Wt_h[4];
    __half* Wt_l[4];
    for (int i = 0; i < 3; ++i) {
        Wt_h[i] = (__half*)alloc((size_t)HID * HID * 2);
        Wt_l[i] = (__half*)alloc((size_t)HID * HID * 2);
    }
    Wt_h[3] = (__half*)alloc((size_t)CLS * HID * 2);
    Wt_l[3] = (__half*)alloc((size_t)CLS * HID * 2);

    // CSR pipeline: counting-sort into bins, then per-bin CSR
    hist_kernel<<<NBLK, 256, 0, stream>>>(col, hist, E, chunk);
    int hBlocks = (HTOT + 255) / 256;  // 196
    block_sum_kernel<<<hBlocks, 256, 0, stream>>>(hist, bsum1, HTOT);
    scan_bsum_kernel<<<1, 256, 0, stream>>>(bsum1, hBlocks);
    scan_final_plain<<<hBlocks, 256, 0, stream>>>(hist, bsum1, hofs, HTOT);
    scatter_kernel<<<NBLK, 256, 0, stream>>>(row, col, hofs, gbuf, E, chunk);
    bin_count_kernel<<<NBINS, 256, 0, stream>>>(hofs, gbuf, cnt, N, E);
    int nBlocks = (N + 255) / 256;  // 196
    block_sum_kernel<<<nBlocks, 256, 0, stream>>>(cnt, bsum2, N);
    scan_bsum_kernel<<<1, 256, 0, stream>>>(bsum2, nBlocks);
    scan_final_kernel<<<nBlocks, 256, 0, stream>>>(cnt, bsum2, row_ptr, dinv, N);
    csr_scatter_kernel<<<NBINS, 256, 0, stream>>>(hofs, gbuf, row_ptr, csr_src, N, E);

    // input cast + weight splits (independent of CSR chain)
    int n4 = N * HID / 4;
    cast_x_kernel<<<(n4 + 255) / 256, 256, 0, stream>>>(x, hA, n4);
    wsplit_all_kernel<<<224, 256, 0, stream>>>(W0, W1, W2, Wl,
        Wt_h[0], Wt_l[0], Wt_h[1], Wt_l[1], Wt_h[2], Wt_l[2], Wt_h[3], Wt_l[3]);

    const int gemmBlocks = (N / 16 + 3) / 4;  // 782 blocks x 4 waves >= 3125 tiles
    const int aggBlocks  = (N + 3) / 4;

    // layer 0
    mfma_gemm_f16<128, false, true><<<gemmBlocks, 256, 0, stream>>>(hA, Wt_h[0], Wt_l[0], nullptr, h2, N);
    agg_kernel<<<aggBlocks, 256, 0, stream>>>(h2, row_ptr, csr_src, dinv, b0, hA, N);
    // layer 1
    mfma_gemm_f16<128, false, true><<<gemmBlocks, 256, 0, stream>>>(hA, Wt_h[1], Wt_l[1], nullptr, h2, N);
    agg_kernel<<<aggBlocks, 256, 0, stream>>>(h2, row_ptr, csr_src, dinv, b1, hA, N);
    // layer 2
    mfma_gemm_f16<128, false, true><<<gemmBlocks, 256, 0, stream>>>(hA, Wt_h[2], Wt_l[2], nullptr, h2, N);
    agg_kernel<<<aggBlocks, 256, 0, stream>>>(h2, row_ptr, csr_src, dinv, b2, hA, N);
    // classifier head
    mfma_gemm_f16<64, true, false><<<gemmBlocks, 256, 0, stream>>>(hA, Wt_h[3], Wt_l[3], bl, out, N);
}

// Round 7
// 340.648 us; speedup vs baseline: 1.8043x; 1.0296x over previous
//
#include <hip/hip_runtime.h>
#include <hip/hip_bf16.h>
#include <hip/hip_fp16.h>

#define N_NODES 50000
#define HID 128
#define CLS 64

#define NBINS 196        // ceil(50000/256) node bins
#define NBLK 256         // hist/scatter blocks
#define LBUF_CAP 4096    // per-bin CSR staging (bin degree ~3277 + 14 sigma)

typedef __attribute__((ext_vector_type(8))) _Float16 f16x8;
typedef __attribute__((ext_vector_type(4))) float f32x4;

// ---------------- pass 1a: per-(block,bin) histogram ----------------
__global__ __launch_bounds__(256) void hist_kernel(const int* __restrict__ col,
                                                   int* __restrict__ hist, int E, int chunk) {
    __shared__ int h[NBINS];
    for (int i = threadIdx.x; i < NBINS; i += 256) h[i] = 0;
    __syncthreads();
    int b = blockIdx.x;
    int beg = b * chunk;
    int end = min(E, beg + chunk);
    if (beg < end) {
        int vend = beg + ((end - beg) >> 2 << 2);
        for (int i = beg + threadIdx.x * 4; i + 3 < vend + 4 && i < vend; i += 1024) {
            int4 c4 = *(const int4*)(col + i);
            atomicAdd(&h[c4.x >> 8], 1);
            atomicAdd(&h[c4.y >> 8], 1);
            atomicAdd(&h[c4.z >> 8], 1);
            atomicAdd(&h[c4.w >> 8], 1);
        }
        int i = vend + threadIdx.x;
        if (i < end) atomicAdd(&h[col[i] >> 8], 1);
    }
    __syncthreads();
    for (int i = threadIdx.x; i < NBINS; i += 256)
        hist[i * NBLK + b] = h[i];  // bin-major, block-minor
}

// ---------------- pass 1b: per-bin scan of its 256 block-counts ----------------
__global__ __launch_bounds__(256) void binscan_kernel(const int* __restrict__ hist,
                                                      int* __restrict__ hlocal,
                                                      int* __restrict__ binTot) {
    __shared__ int s[256];
    int i = blockIdx.x, t = threadIdx.x;
    int v = hist[i * NBLK + t];
    s[t] = v;
    __syncthreads();
#pragma unroll
    for (int off = 1; off < 256; off <<= 1) {
        int u = (t >= off) ? s[t - off] : 0;
        __syncthreads();
        s[t] += u;
        __syncthreads();
    }
    hlocal[i * NBLK + t] = s[t] - v;
    if (t == 255) binTot[i] = s[255];
}

// ---------------- tiny exclusive scan (n <= 256), out[n] = total ----------------
__global__ __launch_bounds__(256) void tiny_scan_kernel(const int* __restrict__ in,
                                                        int* __restrict__ out, int n) {
    __shared__ int s[256];
    int t = threadIdx.x;
    int v = (t < n) ? in[t] : 0;
    s[t] = v;
    __syncthreads();
#pragma unroll
    for (int off = 1; off < 256; off <<= 1) {
        int u = (t >= off) ? s[t - off] : 0;
        __syncthreads();
        s[t] += u;
        __syncthreads();
    }
    if (t < n) out[t] = s[t] - v;
    if (t == 255) out[n] = s[255];
}

// ---------------- pass 1c: scatter edges bin-sorted (src 4B + colLow 1B) ---------
__global__ __launch_bounds__(256) void scatter_kernel(
    const int* __restrict__ row, const int* __restrict__ col,
    const int* __restrict__ binBase, const int* __restrict__ hlocal,
    int* __restrict__ sbuf_src, unsigned char* __restrict__ sbuf_c,
    int E, int chunk) {
    __shared__ int cur[NBINS];
    int b = blockIdx.x;
    for (int i = threadIdx.x; i < NBINS; i += 256)
        cur[i] = binBase[i] + hlocal[i * NBLK + b];
    __syncthreads();
    int beg = b * chunk;
    int end = min(E, beg + chunk);
    if (beg >= end) return;
    int vend = beg + ((end - beg) >> 2 << 2);
    for (int i = beg + threadIdx.x * 4; i < vend; i += 1024) {
        int4 c4 = *(const int4*)(col + i);
        int4 r4 = *(const int4*)(row + i);
        int p;
        p = atomicAdd(&cur[c4.x >> 8], 1); sbuf_src[p] = r4.x; sbuf_c[p] = (unsigned char)(c4.x & 255);
        p = atomicAdd(&cur[c4.y >> 8], 1); sbuf_src[p] = r4.y; sbuf_c[p] = (unsigned char)(c4.y & 255);
        p = atomicAdd(&cur[c4.z >> 8], 1); sbuf_src[p] = r4.z; sbuf_c[p] = (unsigned char)(c4.z & 255);
        p = atomicAdd(&cur[c4.w >> 8], 1); sbuf_src[p] = r4.w; sbuf_c[p] = (unsigned char)(c4.w & 255);
    }
    int i = vend + threadIdx.x;
    if (i < end) {
        int c = col[i];
        int p = atomicAdd(&cur[c >> 8], 1);
        sbuf_src[p] = row[i];
        sbuf_c[p] = (unsigned char)(c & 255);
    }
}

// ---------------- pass 2a: per-node degree -> dinv + per-bin total ----------------
__global__ __launch_bounds__(256) void csr_count_kernel(
    const int* __restrict__ binBase, const unsigned char* __restrict__ sbuf_c,
    float* __restrict__ dinv, int* __restrict__ nodeTot, int n) {
    __shared__ int lcnt[256];
    __shared__ int s[256];
    int t = threadIdx.x, i = blockIdx.x;
    lcnt[t] = 0;
    __syncthreads();
    int beg = binBase[i], end = binBase[i + 1];
    for (int j = beg + t; j < end; j += 256)
        atomicAdd(&lcnt[sbuf_c[j]], 1);
    __syncthreads();
    int deg = lcnt[t];
    int node = i * 256 + t;
    if (node < n) dinv[node] = rsqrtf((float)deg + 1.0f);
    s[t] = deg;
    __syncthreads();
#pragma unroll
    for (int off = 128; off; off >>= 1) {
        if (t < off) s[t] += s[t + off];
        __syncthreads();
    }
    if (t == 0) nodeTot[i] = s[0];
}

// ---------------- pass 2b: absolute row_ptr + CSR (src,w) coalesced ----------------
__global__ __launch_bounds__(256) void csr_place_kernel(
    const int* __restrict__ binBase, const int* __restrict__ nodeBase,
    const int* __restrict__ sbuf_src, const unsigned char* __restrict__ sbuf_c,
    const float* __restrict__ dinv, int* __restrict__ row_ptr,
    int2* __restrict__ csr_sw, int n) {
    __shared__ int lcnt[256];
    __shared__ int lcur[256];
    __shared__ int ss[256];
    __shared__ float dloc[256];
    __shared__ int2 lbuf[LBUF_CAP];
    int t = threadIdx.x, i = blockIdx.x;
    lcnt[t] = 0;
    int node = i * 256 + t;
    dloc[t] = (node < n) ? dinv[node] : 0.f;
    __syncthreads();
    int beg = binBase[i], end = binBase[i + 1];
    for (int j = beg + t; j < end; j += 256)
        atomicAdd(&lcnt[sbuf_c[j]], 1);
    __syncthreads();
    int v = lcnt[t];
    ss[t] = v;
    __syncthreads();
#pragma unroll
    for (int off = 1; off < 256; off <<= 1) {
        int u = (t >= off) ? ss[t - off] : 0;
        __syncthreads();
        ss[t] += u;
        __syncthreads();
    }
    int excl = ss[t] - v;
    lcur[t] = excl;
    int total = ss[255];
    int base = nodeBase[i];
    if (node < n) row_ptr[node] = base + excl;
    if (i == 0 && t == 0) row_ptr[n] = nodeBase[NBINS];
    __syncthreads();
    for (int j = beg + t; j < end; j += 256) {
        int c = sbuf_c[j];
        int src = sbuf_src[j];
        int pos = atomicAdd(&lcur[c], 1);
        float w = dinv[src] * dloc[c];
        lbuf[pos] = make_int2(src, __float_as_int(w));
    }
    __syncthreads();
    for (int j = t; j < total; j += 256) csr_sw[base + j] = lbuf[j];
}

// ---------------- fused: x fp32->fp16 cast + all-W transpose/split ----------------
#define CAST_T (N_NODES * HID / 4)   // 1,600,000 float4 groups
__global__ __launch_bounds__(256) void castw_kernel(
    const float* __restrict__ x, __half* __restrict__ hA,
    const float* __restrict__ W0, const float* __restrict__ W1,
    const float* __restrict__ W2, const float* __restrict__ Wl,
    __half* __restrict__ o0h, __half* __restrict__ o0l,
    __half* __restrict__ o1h, __half* __restrict__ o1l,
    __half* __restrict__ o2h, __half* __restrict__ o2l,
    __half* __restrict__ o3h, __half* __restrict__ o3l) {
    int idx = blockIdx.x * 256 + threadIdx.x;
    if (idx < CAST_T) {
        float4 v = ((const float4*)x)[idx];
        ((__half2*)hA)[idx * 2] = __float22half2_rn(make_float2(v.x, v.y));
        ((__half2*)hA)[idx * 2 + 1] = __float22half2_rn(make_float2(v.z, v.w));
        return;
    }
    int widx = idx - CAST_T;
    const float* W;
    __half *oh, *ol;
    int NCdim, local;
    if (widx < 16384)      { W = W0; oh = o0h; ol = o0l; NCdim = 128; local = widx; }
    else if (widx < 32768) { W = W1; oh = o1h; ol = o1l; NCdim = 128; local = widx - 16384; }
    else if (widx < 49152) { W = W2; oh = o2h; ol = o2l; NCdim = 128; local = widx - 32768; }
    else if (widx < 57344) { W = Wl; oh = o3h; ol = o3l; NCdim = 64;  local = widx - 49152; }
    else return;
    int nn = local >> 7;
    int k = local & 127;
    float v = W[(size_t)k * NCdim + nn];
    __half h = __float2half_rn(v);
    oh[local] = h;
    ol[local] = __float2half_rn(v - __half2float(h));
}

// ---------------- f16 MFMA GEMM: C = A @ (Wh+Wl) (+bias), K=128 ----------------
template<int NC, bool ADD_BIAS, bool HALF_OUT>
__global__ __launch_bounds__(256) void mfma_gemm_f16(
    const __half* __restrict__ A, const __half* __restrict__ Bh,
    const __half* __restrict__ Bl, const float* __restrict__ bias,
    void* __restrict__ Cv, int M) {
    constexpr int NT = NC / 16;
    int lane = threadIdx.x & 63;
    int rowTile = blockIdx.x * 4 + (threadIdx.x >> 6);
    int m0 = rowTile << 4;
    if (m0 >= M) return;
    int mr = lane & 15;
    int kq = (lane >> 4) << 3;  // 0,8,16,24

    const __half* ap = A + (size_t)(m0 + mr) * 128 + kq;
    const __half* bh = Bh + (size_t)mr * 128 + kq;
    const __half* bl = Bl + (size_t)mr * 128 + kq;

    f32x4 acc[NT];
#pragma unroll
    for (int t = 0; t < NT; ++t) acc[t] = (f32x4){0.f, 0.f, 0.f, 0.f};

#pragma unroll
    for (int kc = 0; kc < 128; kc += 32) {
        f16x8 a = *(const f16x8*)(ap + kc);
#pragma unroll
        for (int t = 0; t < NT; ++t) {
            f16x8 wh = *(const f16x8*)(bh + (size_t)t * 16 * 128 + kc);
            f16x8 wl = *(const f16x8*)(bl + (size_t)t * 16 * 128 + kc);
            acc[t] = __builtin_amdgcn_mfma_f32_16x16x32_f16(a, wh, acc[t], 0, 0, 0);
            acc[t] = __builtin_amdgcn_mfma_f32_16x16x32_f16(a, wl, acc[t], 0, 0, 0);
        }
    }

    // C/D layout: col = lane&15, row = (lane>>4)*4 + reg
    int r0 = m0 + ((lane >> 4) << 2);
    int cc = lane & 15;
#pragma unroll
    for (int t = 0; t < NT; ++t) {
        float bsv = ADD_BIAS ? bias[t * 16 + cc] : 0.f;
#pragma unroll
        for (int r = 0; r < 4; ++r) {
            float val = acc[t][r] + bsv;
            size_t idx = (size_t)(r0 + r) * NC + t * 16 + cc;
            if (HALF_OUT)
                ((__half*)Cv)[idx] = __float2half_rn(val);
            else
                ((float*)Cv)[idx] = val;
        }
    }
}

// ---------------- aggregation: one wave per node, (src,w) packed edges -----------
__global__ __launch_bounds__(256) void agg_kernel(
    const __half* __restrict__ h2, const int* __restrict__ row_ptr,
    const int2* __restrict__ csr_sw, const float* __restrict__ dinv,
    const float* __restrict__ bias, __half* __restrict__ outA, int n) {
    int wid = (blockIdx.x * 256 + threadIdx.x) >> 6;
    int lane = threadIdx.x & 63;
    if (wid >= n) return;
    int beg = row_ptr[wid];
    int end = row_ptr[wid + 1];
    float dv = dinv[wid];
    float ax = 0.f, ay = 0.f;
    int loff = lane << 1;
    for (int base = beg; base < end; base += 64) {
        int cnt = end - base;
        if (cnt > 64) cnt = 64;
        int msrc = 0;
        float mw = 0.f;
        if (lane < cnt) {
            int2 e = csr_sw[base + lane];
            msrc = e.x;
            mw = __int_as_float(e.y);
        }
        int j = 0;
        for (; j + 8 <= cnt; j += 8) {
            int s0 = __shfl(msrc, j),     s1 = __shfl(msrc, j + 1);
            int s2 = __shfl(msrc, j + 2), s3 = __shfl(msrc, j + 3);
            int s4 = __shfl(msrc, j + 4), s5 = __shfl(msrc, j + 5);
            int s6 = __shfl(msrc, j + 6), s7 = __shfl(msrc, j + 7);
            float w0 = __shfl(mw, j),     w1 = __shfl(mw, j + 1);
            float w2 = __shfl(mw, j + 2), w3 = __shfl(mw, j + 3);
            float w4 = __shfl(mw, j + 4), w5 = __shfl(mw, j + 5);
            float w6 = __shfl(mw, j + 6), w7 = __shfl(mw, j + 7);
            float2 v0 = __half22float2(*(const __half2*)(h2 + ((size_t)s0 << 7) + loff));
            float2 v1 = __half22float2(*(const __half2*)(h2 + ((size_t)s1 << 7) + loff));
            float2 v2 = __half22float2(*(const __half2*)(h2 + ((size_t)s2 << 7) + loff));
            float2 v3 = __half22float2(*(const __half2*)(h2 + ((size_t)s3 << 7) + loff));
            float2 v4 = __half22float2(*(const __half2*)(h2 + ((size_t)s4 << 7) + loff));
            float2 v5 = __half22float2(*(const __half2*)(h2 + ((size_t)s5 << 7) + loff));
            float2 v6 = __half22float2(*(const __half2*)(h2 + ((size_t)s6 << 7) + loff));
            float2 v7 = __half22float2(*(const __half2*)(h2 + ((size_t)s7 << 7) + loff));
            ax = fmaf(v0.x, w0, ax); ay = fmaf(v0.y, w0, ay);
            ax = fmaf(v1.x, w1, ax); ay = fmaf(v1.y, w1, ay);
            ax = fmaf(v2.x, w2, ax); ay = fmaf(v2.y, w2, ay);
            ax = fmaf(v3.x, w3, ax); ay = fmaf(v3.y, w3, ay);
            ax = fmaf(v4.x, w4, ax); ay = fmaf(v4.y, w4, ay);
            ax = fmaf(v5.x, w5, ax); ay = fmaf(v5.y, w5, ay);
            ax = fmaf(v6.x, w6, ax); ay = fmaf(v6.y, w6, ay);
            ax = fmaf(v7.x, w7, ax); ay = fmaf(v7.y, w7, ay);
        }
        for (; j + 4 <= cnt; j += 4) {
            int s0 = __shfl(msrc, j),     s1 = __shfl(msrc, j + 1);
            int s2 = __shfl(msrc, j + 2), s3 = __shfl(msrc, j + 3);
            float w0 = __shfl(mw, j),     w1 = __shfl(mw, j + 1);
            float w2 = __shfl(mw, j + 2), w3 = __shfl(mw, j + 3);
            float2 v0 = __half22float2(*(const __half2*)(h2 + ((size_t)s0 << 7) + loff));
            float2 v1 = __half22float2(*(const __half2*)(h2 + ((size_t)s1 << 7) + loff));
            float2 v2 = __half22float2(*(const __half2*)(h2 + ((size_t)s2 << 7) + loff));
            float2 v3 = __half22float2(*(const __half2*)(h2 + ((size_t)s3 << 7) + loff));
            ax = fmaf(v0.x, w0, ax); ay = fmaf(v0.y, w0, ay);
            ax = fmaf(v1.x, w1, ax); ay = fmaf(v1.y, w1, ay);
            ax = fmaf(v2.x, w2, ax); ay = fmaf(v2.y, w2, ay);
            ax = fmaf(v3.x, w3, ax); ay = fmaf(v3.y, w3, ay);
        }
        for (; j < cnt; ++j) {
            int s = __shfl(msrc, j);
            float w = __shfl(mw, j);
            float2 v = __half22float2(*(const __half2*)(h2 + ((size_t)s << 7) + loff));
            ax = fmaf(v.x, w, ax); ay = fmaf(v.y, w, ay);
        }
    }
    float sn = dv * dv;
    float2 self = __half22float2(*(const __half2*)(h2 + ((size_t)wid << 7) + loff));
    float2 b = *(const float2*)(bias + loff);
    float ox = fmaxf(fmaf(self.x, sn, ax) + b.x, 0.f);
    float oy = fmaxf(fmaf(self.y, sn, ay) + b.y, 0.f);
    *(__half2*)(outA + ((size_t)wid << 7) + loff) = __float22half2_rn(make_float2(ox, oy));
}

extern "C" void kernel_launch(void* const* d_in, const int* in_sizes, int n_in,
                              void* d_out, int out_size, void* d_ws, size_t ws_size,
                              hipStream_t stream) {
    const float* x  = (const float*)d_in[0];
    const int* ei   = (const int*)d_in[1];
    const float* W0 = (const float*)d_in[2];
    const float* b0 = (const float*)d_in[3];
    const float* W1 = (const float*)d_in[4];
    const float* b1 = (const float*)d_in[5];
    const float* W2 = (const float*)d_in[6];
    const float* b2 = (const float*)d_in[7];
    const float* Wl = (const float*)d_in[8];
    const float* bl = (const float*)d_in[9];
    float* out = (float*)d_out;

    const int N = N_NODES;
    const int E = in_sizes[1] / 2;
    const int* row = ei;
    const int* col = ei + E;
    const int chunk = (((E + NBLK - 1) / NBLK) + 3) & ~3;  // 4-aligned chunks

    char* ws = (char*)d_ws;
    auto alloc = [&](size_t bytes) {
        char* p = ws;
        ws += (bytes + 255) & ~(size_t)255;
        return p;
    };
    int*   hist    = (int*)alloc((size_t)NBINS * NBLK * 4);
    int*   hlocal  = (int*)alloc((size_t)NBINS * NBLK * 4);
    int*   binTot  = (int*)alloc((size_t)NBINS * 4);
    int*   binBase = (int*)alloc((size_t)(NBINS + 1) * 4);
    int*   nodeTot = (int*)alloc((size_t)NBINS * 4);
    int*   nodeBase= (int*)alloc((size_t)(NBINS + 1) * 4);
    int*   sbuf_src= (int*)alloc((size_t)E * 4);
    unsigned char* sbuf_c = (unsigned char*)alloc((size_t)E);
    int*   row_ptr = (int*)alloc((size_t)(N + 1) * 4);
    float* dinv    = (float*)alloc((size_t)N * 4);
    int2*  csr_sw  = (int2*)alloc((size_t)E * 8);
    __half* h2     = (__half*)alloc((size_t)N * HID * 2);  // GEMM out (gather source)
    __half* hA     = (__half*)alloc((size_t)N * HID * 2);  // agg out (next GEMM A)
    __half* Wt_h[4];
    __half* Wt_l[4];
    for (int i = 0; i < 3; ++i) {
        Wt_h[i] = (__half*)alloc((size_t)HID * HID * 2);
        Wt_l[i] = (__half*)alloc((size_t)HID * HID * 2);
    }
    Wt_h[3] = (__half*)alloc((size_t)CLS * HID * 2);
    Wt_l[3] = (__half*)alloc((size_t)CLS * HID * 2);

    // fused cast + weight split (independent of CSR chain)
    const int castwBlocks = (CAST_T + 57344 + 255) / 256;
    castw_kernel<<<castwBlocks, 256, 0, stream>>>(x, hA, W0, W1, W2, Wl,
        Wt_h[0], Wt_l[0], Wt_h[1], Wt_l[1], Wt_h[2], Wt_l[2], Wt_h[3], Wt_l[3]);

    // CSR pipeline: two-level counting sort, then per-bin CSR with packed (src,w)
    hist_kernel<<<NBLK, 256, 0, stream>>>(col, hist, E, chunk);
    binscan_kernel<<<NBINS, 256, 0, stream>>>(hist, hlocal, binTot);
    tiny_scan_kernel<<<1, 256, 0, stream>>>(binTot, binBase, NBINS);
    scatter_kernel<<<NBLK, 256, 0, stream>>>(row, col, binBase, hlocal, sbuf_src, sbuf_c, E, chunk);
    csr_count_kernel<<<NBINS, 256, 0, stream>>>(binBase, sbuf_c, dinv, nodeTot, N);
    tiny_scan_kernel<<<1, 256, 0, stream>>>(nodeTot, nodeBase, NBINS);
    csr_place_kernel<<<NBINS, 256, 0, stream>>>(binBase, nodeBase, sbuf_src, sbuf_c,
                                                dinv, row_ptr, csr_sw, N);

    const int gemmBlocks = (N / 16 + 3) / 4;  // 782 blocks x 4 waves >= 3125 tiles
    const int aggBlocks  = (N + 3) / 4;

    // layer 0
    mfma_gemm_f16<128, false, true><<<gemmBlocks, 256, 0, stream>>>(hA, Wt_h[0], Wt_l[0], nullptr, h2, N);
    agg_kernel<<<aggBlocks, 256, 0, stream>>>(h2, row_ptr, csr_sw, dinv, b0, hA, N);
    // layer 1
    mfma_gemm_f16<128, false, true><<<gemmBlocks, 256, 0, stream>>>(hA, Wt_h[1], Wt_l[1], nullptr, h2, N);
    agg_kernel<<<aggBlocks, 256, 0, stream>>>(h2, row_ptr, csr_sw, dinv, b1, hA, N);
    // layer 2
    mfma_gemm_f16<128, false, true><<<gemmBlocks, 256, 0, stream>>>(hA, Wt_h[2], Wt_l[2], nullptr, h2, N);
    agg_kernel<<<aggBlocks, 256, 0, stream>>>(h2, row_ptr, csr_sw, dinv, b2, hA, N);
    // classifier head
    mfma_gemm_f16<64, true, false><<<gemmBlocks, 256, 0, stream>>>(hA, Wt_h[3], Wt_l[3], bl, out, N);
}